// Round 5
// baseline (682.257 us; speedup 1.0000x reference)
//
#include <hip/hip_runtime.h>

#define N_NODES 50000
#define N_EDGES 800000
#define N_GRAPHS 50
#define D 128
#define D_OUT 10
#define PLANE_F4 200000   // per-slice plane: 50000 nodes * 4 float4 (16 floats)
#define NB 196            // coarse buckets: dst>>8 (49999>>8 == 195)
#define NBLK 196          // partition blocks (196*4096 >= 800000)
#define NT 196            // spmm node-tiles per slice (196*256 >= 50000)

// ---------------------------------------------------------------------------
// 1) Coarse partition histogram (LDS, no device atomics for dst) + src
//    out-degree histogram (the one unavoidable device-atomic stream).
// ---------------------------------------------------------------------------
__global__ __launch_bounds__(256) void part_hist_src(const int* __restrict__ src,
                                                     const int* __restrict__ dst,
                                                     int* __restrict__ gh,
                                                     int* __restrict__ out_deg) {
    __shared__ int lh[NB];
    int tid = threadIdx.x, blk = blockIdx.x;
    if (tid < NB) lh[tid] = 0;
    __syncthreads();
    int base = blk * 4096;
    #pragma unroll
    for (int j = 0; j < 16; j++) {
        int i = base + j * 256 + tid;
        if (i < N_EDGES) {
            atomicAdd(&out_deg[src[i]], 1);          // device atomic (src stream)
            atomicAdd(&lh[dst[i] >> 8], 1);          // LDS atomic (dst stream)
        }
    }
    __syncthreads();
    if (tid < NB) gh[tid * NBLK + blk] = lh[tid];
}

// ---------------------------------------------------------------------------
// 2) Exclusive scan of gh[NB*NBLK = 38416], single block, ONE block-scan:
//    38 serial elems/thread -> 1024-thread block scan -> writeback pass.
// ---------------------------------------------------------------------------
__global__ __launch_bounds__(1024) void part_scan(int* __restrict__ gh) {
    const int N = NB * NBLK;            // 38416
    const int PER = 38;                 // 1024*38 = 38912 >= N
    __shared__ int wsum[16];
    int t = threadIdx.x;
    int lane = t & 63, wid = t >> 6;
    int base = t * PER;
    int sum = 0;
    #pragma unroll 4
    for (int j = 0; j < PER; j++) {
        int i = base + j;
        if (i < N) sum += gh[i];
    }
    // block-exclusive scan of per-thread sums
    int x = sum;
    #pragma unroll
    for (int d = 1; d < 64; d <<= 1) {
        int y = __shfl_up(x, d, 64);
        if (lane >= d) x += y;
    }
    if (lane == 63) wsum[wid] = x;
    __syncthreads();
    if (wid == 0) {
        int v = (lane < 16) ? wsum[lane] : 0;
        #pragma unroll
        for (int d = 1; d < 16; d <<= 1) {
            int y = __shfl_up(v, d, 64);
            if (lane >= d) v += y;
        }
        if (lane < 16) wsum[lane] = v;
    }
    __syncthreads();
    int woff = (wid == 0) ? 0 : wsum[wid - 1];
    int run = woff + x - sum;           // exclusive base for this thread
    #pragma unroll 4
    for (int j = 0; j < PER; j++) {
        int i = base + j;
        if (i < N) { int v = gh[i]; gh[i] = run; run += v; }
    }
}

// ---------------------------------------------------------------------------
// 3) Partition scatter: LDS cursors (shared-memory atomics only). Writes
//    packed ((dst&255)<<16)|src into the coarse-bucket-partitioned array.
// ---------------------------------------------------------------------------
__global__ __launch_bounds__(256) void part_scatter(const int* __restrict__ src,
                                                    const int* __restrict__ dst,
                                                    const int* __restrict__ gh,
                                                    unsigned int* __restrict__ packed) {
    __shared__ int lc[NB];
    int tid = threadIdx.x, blk = blockIdx.x;
    if (tid < NB) lc[tid] = gh[tid * NBLK + blk];
    __syncthreads();
    int base = blk * 4096;
    #pragma unroll
    for (int j = 0; j < 16; j++) {
        int i = base + j * 256 + tid;
        if (i < N_EDGES) {
            int d = dst[i];
            int s = src[i];
            int p = atomicAdd(&lc[d >> 8], 1);       // LDS atomic
            packed[p] = ((unsigned int)(d & 255) << 16) | (unsigned int)s;
        }
    }
}

// ---------------------------------------------------------------------------
// 4) Per-bucket CSR build: one block per coarse bucket (~4096 edges, <=8192).
//    LDS-staged: 256-bin hist -> block scan -> row_ptr + nd + coalesced col16.
// ---------------------------------------------------------------------------
__global__ __launch_bounds__(256) void bucket_csr(const unsigned int* __restrict__ packed,
                                                  const int* __restrict__ gh,
                                                  unsigned short* __restrict__ col16,
                                                  int* __restrict__ row_ptr,
                                                  float* __restrict__ nd) {
    __shared__ unsigned int ep[8192];
    __shared__ unsigned short lcol[8192];
    __shared__ int hist[256], cur[256], wsum[4];
    int t = threadIdx.x, b = blockIdx.x;
    int nb = gh[b * NBLK];
    int ne = (b < NB - 1) ? gh[(b + 1) * NBLK] : N_EDGES;
    int cnt = ne - nb;
    if (cnt > 8192) cnt = 8192;         // statistically unreachable guard
    hist[t] = 0;
    __syncthreads();
    for (int i = t; i < cnt; i += 256) {
        unsigned int e = packed[nb + i];
        ep[i] = e;
        atomicAdd(&hist[e >> 16], 1);
    }
    __syncthreads();
    int v = hist[t];
    int lane = t & 63, w = t >> 6;
    int x = v;
    #pragma unroll
    for (int d = 1; d < 64; d <<= 1) {
        int y = __shfl_up(x, d, 64);
        if (lane >= d) x += y;
    }
    if (lane == 63) wsum[w] = x;
    __syncthreads();
    int add = 0;
    #pragma unroll
    for (int i = 0; i < 4; i++) if (i < w) add += wsum[i];
    int excl = add + x - v;
    cur[t] = excl;
    int node = b * 256 + t;
    if (node < N_NODES) {
        row_ptr[node] = nb + excl;
        int id = v > 1 ? v : 1;
        nd[node] = 1.0f / sqrtf((float)id);
    }
    if (b == NB - 1 && t == 0) row_ptr[N_NODES] = N_EDGES;
    __syncthreads();
    for (int i = t; i < cnt; i += 256) {
        unsigned int e = ep[i];
        int p = atomicAdd(&cur[e >> 16], 1);         // LDS atomic
        lcol[p] = (unsigned short)(e & 0xFFFF);
    }
    __syncthreads();
    for (int i = t; i < cnt; i += 256) col16[nb + i] = lcol[i];
}

// ---------------------------------------------------------------------------
// 5) Prescale + slice: xs[p][node][16] = out_deg[node]^-1/2 * h[node][p*16..].
// ---------------------------------------------------------------------------
__global__ __launch_bounds__(256) void prescale_k(const float* __restrict__ h,
                                                  const int* __restrict__ out_deg,
                                                  float* __restrict__ out) {
    int i = blockIdx.x * 256 + threadIdx.x;      // over 1,600,000 float4s
    if (i < N_NODES * 32) {
        int node = i >> 5;
        int kg = i & 31;
        float4 v = ((const float4*)h)[i];
        int od = out_deg[node];
        float s = 1.0f / sqrtf((float)(od > 1 ? od : 1));
        int p = kg >> 2, q = kg & 3;
        ((float4*)out)[p * PLANE_F4 + node * 4 + q] =
            make_float4(v.x * s, v.y * s, v.z * s, v.w * s);
    }
}

// ---------------------------------------------------------------------------
// 6) Feature-sliced SpMM with HW-derived XCD affinity + flat-4 scheduling.
//    Round-4 lesson: slice=blockIdx&7 is NOT reliably the XCD at all grid
//    shapes (FETCH 23.8->187MB). Here each block reads its physical XCD id
//    (HW_REG_XCC_ID, measured 0-7 on MI355X) and CLAIMS a (slice,tile) from
//    per-slice queues, own-XCD slice first, stealing only when drained.
//    Coverage proof: a block exits unclaimed only after seeing all counters
//    >= NT, which implies all tiles claimed; grid == total tiles.
//    Correctness never depends on the hwreg value -- only locality does.
// ---------------------------------------------------------------------------
__global__ __launch_bounds__(256) void spmm_k(const float* __restrict__ x,   // sliced
                                              const int* __restrict__ row_ptr,
                                              const unsigned short* __restrict__ col,
                                              const float* __restrict__ nd,
                                              int* __restrict__ qcnt,        // [8]
                                              float* __restrict__ out) {     // sliced
    __shared__ int sinfo[2];
    if (threadIdx.x == 0) {
        unsigned my;
        asm volatile("s_getreg_b32 %0, hwreg(HW_REG_XCC_ID, 0, 4)" : "=s"(my));
        int slice = -1, tile = -1;
        #pragma unroll
        for (int k = 0; k < 8; k++) {
            int s = ((int)my + k) & 7;
            int t = atomicAdd(&qcnt[s], 1);
            if (t < NT) { slice = s; tile = t; break; }
        }
        sinfo[0] = slice; sinfo[1] = tile;
    }
    __syncthreads();
    int slice = sinfo[0];
    if (slice < 0) return;
    int n0 = sinfo[1] * 256 + ((threadIdx.x >> 2) << 2);   // 4 nodes per group
    if (n0 >= N_NODES) return;
    int q = threadIdx.x & 3;
    int nhi = n0 + 4; if (nhi > N_NODES) nhi = N_NODES;
    int e    = row_ptr[n0];
    int eend = row_ptr[nhi];
    int cur  = n0;
    int nbnd = row_ptr[cur + 1];
    const float4* xp = (const float4*)x + slice * PLANE_F4;
    float4* op = (float4*)out + slice * PLANE_F4;
    float4 acc = make_float4(0.f, 0.f, 0.f, 0.f);

#define SPMM_STAGE(HV)                                                        \
    while (e >= nbnd) {                                                       \
        float nv = nd[cur];                                                   \
        op[cur * 4 + q] = make_float4(acc.x * nv, acc.y * nv,                 \
                                      acc.z * nv, acc.w * nv);                \
        acc = make_float4(0.f, 0.f, 0.f, 0.f);                                \
        ++cur; nbnd = row_ptr[cur + 1];                                       \
    }                                                                         \
    acc.x += HV.x; acc.y += HV.y; acc.z += HV.z; acc.w += HV.w;               \
    ++e;

    while (e + 4 <= eend) {
        int c0 = col[e], c1 = col[e + 1], c2 = col[e + 2], c3 = col[e + 3];
        float4 h0 = xp[c0 * 4 + q];
        float4 h1 = xp[c1 * 4 + q];
        float4 h2 = xp[c2 * 4 + q];
        float4 h3 = xp[c3 * 4 + q];
        SPMM_STAGE(h0)
        SPMM_STAGE(h1)
        SPMM_STAGE(h2)
        SPMM_STAGE(h3)
    }
    while (e < eend) {
        int c0 = col[e];
        float4 h0 = xp[c0 * 4 + q];
        SPMM_STAGE(h0)
    }
#undef SPMM_STAGE
    for (; cur < nhi; ++cur) {
        float nv = nd[cur];
        op[cur * 4 + q] = make_float4(acc.x * nv, acc.y * nv,
                                      acc.z * nv, acc.w * nv);
        acc = make_float4(0.f, 0.f, 0.f, 0.f);
    }
}

// ---------------------------------------------------------------------------
// 7) GEMM + bias + ReLU (unchanged, known-good round-3 shape).
//    MODE 0: out = odeg^-1/2 * relu(A@W+b), SLICED. MODE 1: normal layout.
// ---------------------------------------------------------------------------
template <int MODE>
__global__ __launch_bounds__(512) void gemm_relu_k(const float* __restrict__ A,  // sliced
                                                   const float* __restrict__ W,
                                                   const float* __restrict__ bias,
                                                   const int* __restrict__ odeg,
                                                   float* __restrict__ out) {
    __shared__ float As_t[128 * 256];   // 128 KB: [k][r]
    int tid = threadIdx.x;
    int row0 = blockIdx.x * 256;
    const float4* A4 = (const float4*)A;

    #pragma unroll
    for (int it = 0; it < 16; it++) {
        int linear = it * 512 + tid;       // 0..8191 float4s
        int p = linear >> 10;              // plane 0..7
        int rem = linear & 1023;
        int r = rem >> 2;                  // local row 0..255
        int q = rem & 3;                   // float4 within 16-float slice
        int row = row0 + r;
        float4 a = (row < N_NODES) ? A4[p * PLANE_F4 + row * 4 + q]
                                   : make_float4(0.f, 0.f, 0.f, 0.f);
        int kb = p * 16 + q * 4;
        As_t[(kb + 0) * 256 + r] = a.x;
        As_t[(kb + 1) * 256 + r] = a.y;
        As_t[(kb + 2) * 256 + r] = a.z;
        As_t[(kb + 3) * 256 + r] = a.w;
    }
    __syncthreads();

    int tc = tid & 15;    // col group: cols tc*8 .. +8
    int tr = tid >> 4;    // 0..31 : rows tr*8 .. +8
    float acc[8][8];
    #pragma unroll
    for (int r = 0; r < 8; r++)
        #pragma unroll
        for (int c = 0; c < 8; c++) acc[r][c] = 0.f;

    const float4* W4 = (const float4*)W;
    #pragma unroll 2
    for (int k = 0; k < 128; k++) {
        float4 w0 = W4[k * 32 + tc * 2];
        float4 w1 = W4[k * 32 + tc * 2 + 1];
        float4 a0 = *(const float4*)(As_t + k * 256 + tr * 8);
        float4 a1 = *(const float4*)(As_t + k * 256 + tr * 8 + 4);
        float av[8] = {a0.x, a0.y, a0.z, a0.w, a1.x, a1.y, a1.z, a1.w};
        float wv[8] = {w0.x, w0.y, w0.z, w0.w, w1.x, w1.y, w1.z, w1.w};
        #pragma unroll
        for (int rr = 0; rr < 8; rr++)
            #pragma unroll
            for (int cc = 0; cc < 8; cc++)
                acc[rr][cc] = fmaf(av[rr], wv[cc], acc[rr][cc]);
    }

    float4 bv0 = ((const float4*)bias)[tc * 2];
    float4 bv1 = ((const float4*)bias)[tc * 2 + 1];
    #pragma unroll
    for (int rr = 0; rr < 8; rr++) {
        int row = row0 + tr * 8 + rr;
        if (row < N_NODES) {
            float4 o0, o1;
            o0.x = fmaxf(acc[rr][0] + bv0.x, 0.f);
            o0.y = fmaxf(acc[rr][1] + bv0.y, 0.f);
            o0.z = fmaxf(acc[rr][2] + bv0.z, 0.f);
            o0.w = fmaxf(acc[rr][3] + bv0.w, 0.f);
            o1.x = fmaxf(acc[rr][4] + bv1.x, 0.f);
            o1.y = fmaxf(acc[rr][5] + bv1.y, 0.f);
            o1.z = fmaxf(acc[rr][6] + bv1.z, 0.f);
            o1.w = fmaxf(acc[rr][7] + bv1.w, 0.f);
            if (MODE == 0) {
                int od = odeg[row];
                float s = 1.0f / sqrtf((float)(od > 1 ? od : 1));
                o0.x *= s; o0.y *= s; o0.z *= s; o0.w *= s;
                o1.x *= s; o1.y *= s; o1.z *= s; o1.w *= s;
                int p = tc >> 1;
                int q0 = (tc & 1) * 2;
                ((float4*)out)[p * PLANE_F4 + row * 4 + q0] = o0;
                ((float4*)out)[p * PLANE_F4 + row * 4 + q0 + 1] = o1;
            } else {
                ((float4*)out)[row * 32 + tc * 2] = o0;
                ((float4*)out)[row * 32 + tc * 2 + 1] = o1;
            }
        }
    }
}

// ---------------------------------------------------------------------------
// 8) Fused projection + readout (unchanged).
// ---------------------------------------------------------------------------
__global__ __launch_bounds__(256) void proj_readout_k(const float* __restrict__ h,
                                                      const int* __restrict__ gid,
                                                      const float* __restrict__ Wm,
                                                      float* __restrict__ hgp,
                                                      int* __restrict__ gcnt) {
    __shared__ float Wmt[10 * 144];
    int tid = threadIdx.x;
    for (int i = tid; i < 1280; i += 256) {
        int k = i / 10, o = i % 10;
        Wmt[o * 144 + k + 4 * (k >> 5)] = Wm[i];
    }
    __syncthreads();

    int v = blockIdx.x * 64 + (tid >> 2);
    int quarter = tid & 3;
    int lane = tid & 63;

    float acc[D_OUT];
    #pragma unroll
    for (int o = 0; o < D_OUT; o++) acc[o] = 0.f;
    int g = -1;
    int cnt = 0;
    if (v < N_NODES) {
        g = gid[v];
        cnt = (quarter == 0) ? 1 : 0;
        const float4* h4 = (const float4*)h + v * 32 + quarter * 8;
        const float* wbase = Wmt + quarter * 36;
        #pragma unroll
        for (int kk = 0; kk < 8; kk++) {
            float4 hv = h4[kk];
            #pragma unroll
            for (int o = 0; o < D_OUT; o++) {
                float4 w = *(const float4*)(wbase + o * 144 + kk * 4);
                acc[o] += hv.x * w.x + hv.y * w.y + hv.z * w.z + hv.w * w.w;
            }
        }
    }

    #pragma unroll
    for (int d = 1; d < 64; d <<= 1) {
        int gp = __shfl_up(g, d, 64);
        int cp = __shfl_up(cnt, d, 64);
        bool take = (lane >= d) && (gp == g);
        #pragma unroll
        for (int o = 0; o < D_OUT; o++) {
            float ap = __shfl_up(acc[o], d, 64);
            if (take) acc[o] += ap;
        }
        if (take) cnt += cp;
    }
    int gn = __shfl_down(g, 1, 64);
    bool tail = (lane == 63) || (gn != g);
    if (tail && g >= 0) {
        #pragma unroll
        for (int o = 0; o < D_OUT; o++) atomicAdd(&hgp[g * D_OUT + o], acc[o]);
        if (cnt > 0) atomicAdd(&gcnt[g], cnt);
    }
}

// ---------------------------------------------------------------------------
// 9) Final: logits = hgp/cnt + bm ; log_softmax over axis 0 (graphs)
// ---------------------------------------------------------------------------
__global__ __launch_bounds__(512) void final_k(const float* __restrict__ hgp,
                                               const int* __restrict__ gcnt,
                                               const float* __restrict__ bm,
                                               float* __restrict__ out) {
    __shared__ float lg[N_GRAPHS * D_OUT];
    __shared__ float colm[D_OUT], colls[D_OUT];
    int tid = threadIdx.x;
    if (tid < N_GRAPHS * D_OUT) {
        int g = tid / D_OUT, o = tid % D_OUT;
        float c = (float)gcnt[g];
        lg[tid] = hgp[tid] / (c > 1.f ? c : 1.f) + bm[o];
    }
    __syncthreads();
    if (tid < D_OUT) {
        float m = -1e30f;
        for (int g = 0; g < N_GRAPHS; g++) m = fmaxf(m, lg[g * D_OUT + tid]);
        float s = 0.f;
        for (int g = 0; g < N_GRAPHS; g++) s += expf(lg[g * D_OUT + tid] - m);
        colm[tid] = m; colls[tid] = logf(s);
    }
    __syncthreads();
    if (tid < N_GRAPHS * D_OUT) {
        int o = tid % D_OUT;
        out[tid] = lg[tid] - colm[o] - colls[o];
    }
}

// ---------------------------------------------------------------------------
// Launch. packed[] aliases bufB head (dead before spmm#1 writes bufB).
// qcnt: 3 banks of 8 (one per spmm launch), zeroed with out_deg/gcnt/hgp.
// Total footprint 53,556,128 B.
// ---------------------------------------------------------------------------
extern "C" void kernel_launch(void* const* d_in, const int* in_sizes, int n_in,
                              void* d_out, int out_size, void* d_ws, size_t ws_size,
                              hipStream_t stream) {
    const float* h_in = (const float*)d_in[0];
    const int*   src  = (const int*)d_in[1];
    const int*   dst  = (const int*)d_in[2];
    const int*   gid  = (const int*)d_in[3];
    const float* W1 = (const float*)d_in[4];  const float* b1 = (const float*)d_in[5];
    const float* W2 = (const float*)d_in[6];  const float* b2 = (const float*)d_in[7];
    const float* W3 = (const float*)d_in[8];  const float* b3 = (const float*)d_in[9];
    const float* Wm = (const float*)d_in[10]; const float* bm = (const float*)d_in[11];

    char* ws = (char*)d_ws;
    int*            row_ptr = (int*)(ws + 0);                     // 50001 ints (pad 200,032)
    unsigned short* col16   = (unsigned short*)(ws + 200032);     // 1,600,000 B
    float*          nd      = (float*)(ws + 1800032);             // 200,000 B
    int*            out_deg = (int*)(ws + 2000032);               // 200,000 B  } zeroed
    int*            gcnt    = (int*)(ws + 2200032);               // 256 B      } together
    float*          hgp     = (float*)(ws + 2200288);             // 2,048 B    } 202,432 B
    int*            qcnt    = (int*)(ws + 2202336);               // 128 B (3x8 used)
    int*            gh      = (int*)(ws + 2202464);               // 153,664 B
    float*          bufA    = (float*)(ws + 2356128);             // 25.6 MB
    float*          bufB    = (float*)(ws + 27956128);            // 25.6 MB -> 53,556,128
    unsigned int*   packed  = (unsigned int*)bufB;                // 3.2 MB alias

    hipMemsetAsync(out_deg, 0, 202432, stream);     // out_deg+gcnt+hgp+qcnt

    part_hist_src<<<NBLK, 256, 0, stream>>>(src, dst, gh, out_deg);
    part_scan<<<1, 1024, 0, stream>>>(gh);
    part_scatter<<<NBLK, 256, 0, stream>>>(src, dst, gh, packed);
    bucket_csr<<<NB, 256, 0, stream>>>(packed, gh, col16, row_ptr, nd);
    prescale_k<<<6250, 256, 0, stream>>>(h_in, out_deg, bufA);

    spmm_k<<<8 * NT, 256, 0, stream>>>(bufA, row_ptr, col16, nd, qcnt + 0, bufB);
    gemm_relu_k<0><<<196, 512, 0, stream>>>(bufB, W1, b1, out_deg, bufA);
    spmm_k<<<8 * NT, 256, 0, stream>>>(bufA, row_ptr, col16, nd, qcnt + 8, bufB);
    gemm_relu_k<0><<<196, 512, 0, stream>>>(bufB, W2, b2, out_deg, bufA);
    spmm_k<<<8 * NT, 256, 0, stream>>>(bufA, row_ptr, col16, nd, qcnt + 16, bufB);
    gemm_relu_k<1><<<196, 512, 0, stream>>>(bufB, W3, b3, out_deg, bufA);

    proj_readout_k<<<782, 256, 0, stream>>>(bufA, gid, Wm, hgp, gcnt);
    final_k<<<1, 512, 0, stream>>>(hgp, gcnt, bm, (float*)d_out);
}

// Round 6
// 521.675 us; speedup vs baseline: 1.3078x; 1.3078x over previous
//
#include <hip/hip_runtime.h>

#define N_NODES 50000
#define N_EDGES 800000
#define N_GRAPHS 50
#define D 128
#define D_OUT 10
#define PLANE_F4 200000   // per-slice plane: 50000 nodes * 4 float4 (16 floats)
#define NB 196            // coarse buckets: dst>>8 (49999>>8 == 195)
#define NBLK 196          // partition blocks (196*4096 >= 800000)

// ---------------------------------------------------------------------------
// 1) Coarse partition histogram for dst (LDS atomics only). The src
//    out-degree atomics moved into part_scatter: there they overlap the
//    vector-memory work instead of serializing a dedicated ~31us kernel
//    (device-atomic ceiling measured ~25.5G atomics/s, rounds 0-2).
// ---------------------------------------------------------------------------
__global__ __launch_bounds__(256) void part_hist(const int* __restrict__ dst,
                                                 int* __restrict__ gh) {
    __shared__ int lh[NB];
    int tid = threadIdx.x, blk = blockIdx.x;
    if (tid < NB) lh[tid] = 0;
    __syncthreads();
    int base = blk * 4096;
    #pragma unroll
    for (int j = 0; j < 16; j++) {
        int i = base + j * 256 + tid;
        if (i < N_EDGES) atomicAdd(&lh[dst[i] >> 8], 1);     // LDS atomic
    }
    __syncthreads();
    if (tid < NB) gh[tid * NBLK + blk] = lh[tid];
}

// ---------------------------------------------------------------------------
// 2) Exclusive scan of gh[NB*NBLK = 38416], single block, one block-scan:
//    38 serial elems/thread -> 1024-thread block scan -> writeback pass.
// ---------------------------------------------------------------------------
__global__ __launch_bounds__(1024) void part_scan(int* __restrict__ gh) {
    const int N = NB * NBLK;            // 38416
    const int PER = 38;                 // 1024*38 = 38912 >= N
    __shared__ int wsum[16];
    int t = threadIdx.x;
    int lane = t & 63, wid = t >> 6;
    int base = t * PER;
    int sum = 0;
    #pragma unroll 4
    for (int j = 0; j < PER; j++) {
        int i = base + j;
        if (i < N) sum += gh[i];
    }
    int x = sum;
    #pragma unroll
    for (int d = 1; d < 64; d <<= 1) {
        int y = __shfl_up(x, d, 64);
        if (lane >= d) x += y;
    }
    if (lane == 63) wsum[wid] = x;
    __syncthreads();
    if (wid == 0) {
        int v = (lane < 16) ? wsum[lane] : 0;
        #pragma unroll
        for (int d = 1; d < 16; d <<= 1) {
            int y = __shfl_up(v, d, 64);
            if (lane >= d) v += y;
        }
        if (lane < 16) wsum[lane] = v;
    }
    __syncthreads();
    int woff = (wid == 0) ? 0 : wsum[wid - 1];
    int run = woff + x - sum;           // exclusive base for this thread
    #pragma unroll 4
    for (int j = 0; j < PER; j++) {
        int i = base + j;
        if (i < N) { int v = gh[i]; gh[i] = run; run += v; }
    }
}

// ---------------------------------------------------------------------------
// 3) Partition scatter (LDS cursors) + src out-degree histogram. The device
//    atomic stream rides the otherwise-idle atomic pipe while the vector
//    pipes do the scatter; out_deg is first consumed by prescale_k (later).
// ---------------------------------------------------------------------------
__global__ __launch_bounds__(256) void part_scatter(const int* __restrict__ src,
                                                    const int* __restrict__ dst,
                                                    const int* __restrict__ gh,
                                                    unsigned int* __restrict__ packed,
                                                    int* __restrict__ out_deg) {
    __shared__ int lc[NB];
    int tid = threadIdx.x, blk = blockIdx.x;
    if (tid < NB) lc[tid] = gh[tid * NBLK + blk];
    __syncthreads();
    int base = blk * 4096;
    #pragma unroll
    for (int j = 0; j < 16; j++) {
        int i = base + j * 256 + tid;
        if (i < N_EDGES) {
            int d = dst[i];
            int s = src[i];
            atomicAdd(&out_deg[s], 1);               // device atomic (src stream)
            int p = atomicAdd(&lc[d >> 8], 1);       // LDS atomic
            packed[p] = ((unsigned int)(d & 255) << 16) | (unsigned int)s;
        }
    }
}

// ---------------------------------------------------------------------------
// 4) Per-bucket CSR build: one block per coarse bucket (~4096 edges, <=8192).
//    LDS-staged: 256-bin hist -> block scan -> row_ptr + nd + coalesced col16.
// ---------------------------------------------------------------------------
__global__ __launch_bounds__(256) void bucket_csr(const unsigned int* __restrict__ packed,
                                                  const int* __restrict__ gh,
                                                  unsigned short* __restrict__ col16,
                                                  int* __restrict__ row_ptr,
                                                  float* __restrict__ nd) {
    __shared__ unsigned int ep[8192];
    __shared__ unsigned short lcol[8192];
    __shared__ int hist[256], cur[256], wsum[4];
    int t = threadIdx.x, b = blockIdx.x;
    int nb = gh[b * NBLK];
    int ne = (b < NB - 1) ? gh[(b + 1) * NBLK] : N_EDGES;
    int cnt = ne - nb;
    if (cnt > 8192) cnt = 8192;         // statistically unreachable guard
    hist[t] = 0;
    __syncthreads();
    for (int i = t; i < cnt; i += 256) {
        unsigned int e = packed[nb + i];
        ep[i] = e;
        atomicAdd(&hist[e >> 16], 1);
    }
    __syncthreads();
    int v = hist[t];
    int lane = t & 63, w = t >> 6;
    int x = v;
    #pragma unroll
    for (int d = 1; d < 64; d <<= 1) {
        int y = __shfl_up(x, d, 64);
        if (lane >= d) x += y;
    }
    if (lane == 63) wsum[w] = x;
    __syncthreads();
    int add = 0;
    #pragma unroll
    for (int i = 0; i < 4; i++) if (i < w) add += wsum[i];
    int excl = add + x - v;
    cur[t] = excl;
    int node = b * 256 + t;
    if (node < N_NODES) {
        row_ptr[node] = nb + excl;
        int id = v > 1 ? v : 1;
        nd[node] = 1.0f / sqrtf((float)id);
    }
    if (b == NB - 1 && t == 0) row_ptr[N_NODES] = N_EDGES;
    __syncthreads();
    for (int i = t; i < cnt; i += 256) {
        unsigned int e = ep[i];
        int p = atomicAdd(&cur[e >> 16], 1);         // LDS atomic
        lcol[p] = (unsigned short)(e & 0xFFFF);
    }
    __syncthreads();
    for (int i = t; i < cnt; i += 256) col16[nb + i] = lcol[i];
}

// ---------------------------------------------------------------------------
// 5) Prescale + slice: xs[p][node][16] = out_deg[node]^-1/2 * h[node][p*16..].
// ---------------------------------------------------------------------------
__global__ __launch_bounds__(256) void prescale_k(const float* __restrict__ h,
                                                  const int* __restrict__ out_deg,
                                                  float* __restrict__ out) {
    int i = blockIdx.x * 256 + threadIdx.x;      // over 1,600,000 float4s
    if (i < N_NODES * 32) {
        int node = i >> 5;
        int kg = i & 31;
        float4 v = ((const float4*)h)[i];
        int od = out_deg[node];
        float s = 1.0f / sqrtf((float)(od > 1 ? od : 1));
        int p = kg >> 2, q = kg & 3;
        ((float4*)out)[p * PLANE_F4 + node * 4 + q] =
            make_float4(v.x * s, v.y * s, v.z * s, v.w * s);
    }
}

// ---------------------------------------------------------------------------
// 6) Feature-sliced SpMM -- ROUND-3 EXACT REVERT (twice-measured 54.4us,
//    FETCH 23.8MB at THIS dispatch shape: grid 6256, 256-thread blocks,
//    slice=b&7, 64 nodes/block). Rounds 4-5 proved the slice<->XCD locality
//    is a property of this exact shape: grid 1568 (r4) and the XCC_ID queue
//    (r5) both re-replicated FETCH to ~188MB. Do not change grid/block/slice
//    mapping without re-measuring FETCH_SIZE.
// ---------------------------------------------------------------------------
__global__ __launch_bounds__(256) void spmm_k(const float* __restrict__ x,   // sliced
                                              const int* __restrict__ row_ptr,
                                              const unsigned short* __restrict__ col,
                                              const float* __restrict__ nd,
                                              float* __restrict__ out) {     // sliced
    int b = blockIdx.x;
    int slice = b & 7;
    int node = (b >> 3) * 64 + (threadIdx.x >> 2);
    if (node >= N_NODES) return;
    int q = threadIdx.x & 3;
    int s = row_ptr[node];
    int e = row_ptr[node + 1];
    const float4* xp = (const float4*)x + slice * PLANE_F4;
    float4 a0 = make_float4(0.f, 0.f, 0.f, 0.f);
    float4 a1 = make_float4(0.f, 0.f, 0.f, 0.f);
    int i = s;
    for (; i + 4 <= e; i += 4) {
        int c0 = col[i], c1 = col[i + 1], c2 = col[i + 2], c3 = col[i + 3];
        float4 h0 = xp[c0 * 4 + q];
        float4 h1 = xp[c1 * 4 + q];
        float4 h2 = xp[c2 * 4 + q];
        float4 h3 = xp[c3 * 4 + q];
        a0.x += h0.x; a0.y += h0.y; a0.z += h0.z; a0.w += h0.w;
        a1.x += h1.x; a1.y += h1.y; a1.z += h1.z; a1.w += h1.w;
        a0.x += h2.x; a0.y += h2.y; a0.z += h2.z; a0.w += h2.w;
        a1.x += h3.x; a1.y += h3.y; a1.z += h3.z; a1.w += h3.w;
    }
    for (; i < e; i++) {
        float4 hv = xp[col[i] * 4 + q];
        a0.x += hv.x; a0.y += hv.y; a0.z += hv.z; a0.w += hv.w;
    }
    float ndv = nd[node];
    ((float4*)out)[slice * PLANE_F4 + node * 4 + q] =
        make_float4((a0.x + a1.x) * ndv, (a0.y + a1.y) * ndv,
                    (a0.z + a1.z) * ndv, (a0.w + a1.w) * ndv);
}

// ---------------------------------------------------------------------------
// 7) GEMM + bias + ReLU (unchanged, known-good round-3 shape).
//    MODE 0: out = odeg^-1/2 * relu(A@W+b), SLICED. MODE 1: normal layout.
// ---------------------------------------------------------------------------
template <int MODE>
__global__ __launch_bounds__(512) void gemm_relu_k(const float* __restrict__ A,  // sliced
                                                   const float* __restrict__ W,
                                                   const float* __restrict__ bias,
                                                   const int* __restrict__ odeg,
                                                   float* __restrict__ out) {
    __shared__ float As_t[128 * 256];   // 128 KB: [k][r]
    int tid = threadIdx.x;
    int row0 = blockIdx.x * 256;
    const float4* A4 = (const float4*)A;

    #pragma unroll
    for (int it = 0; it < 16; it++) {
        int linear = it * 512 + tid;       // 0..8191 float4s
        int p = linear >> 10;              // plane 0..7
        int rem = linear & 1023;
        int r = rem >> 2;                  // local row 0..255
        int q = rem & 3;                   // float4 within 16-float slice
        int row = row0 + r;
        float4 a = (row < N_NODES) ? A4[p * PLANE_F4 + row * 4 + q]
                                   : make_float4(0.f, 0.f, 0.f, 0.f);
        int kb = p * 16 + q * 4;
        As_t[(kb + 0) * 256 + r] = a.x;
        As_t[(kb + 1) * 256 + r] = a.y;
        As_t[(kb + 2) * 256 + r] = a.z;
        As_t[(kb + 3) * 256 + r] = a.w;
    }
    __syncthreads();

    int tc = tid & 15;    // col group: cols tc*8 .. +8
    int tr = tid >> 4;    // 0..31 : rows tr*8 .. +8
    float acc[8][8];
    #pragma unroll
    for (int r = 0; r < 8; r++)
        #pragma unroll
        for (int c = 0; c < 8; c++) acc[r][c] = 0.f;

    const float4* W4 = (const float4*)W;
    #pragma unroll 2
    for (int k = 0; k < 128; k++) {
        float4 w0 = W4[k * 32 + tc * 2];
        float4 w1 = W4[k * 32 + tc * 2 + 1];
        float4 a0 = *(const float4*)(As_t + k * 256 + tr * 8);
        float4 a1 = *(const float4*)(As_t + k * 256 + tr * 8 + 4);
        float av[8] = {a0.x, a0.y, a0.z, a0.w, a1.x, a1.y, a1.z, a1.w};
        float wv[8] = {w0.x, w0.y, w0.z, w0.w, w1.x, w1.y, w1.z, w1.w};
        #pragma unroll
        for (int rr = 0; rr < 8; rr++)
            #pragma unroll
            for (int cc = 0; cc < 8; cc++)
                acc[rr][cc] = fmaf(av[rr], wv[cc], acc[rr][cc]);
    }

    float4 bv0 = ((const float4*)bias)[tc * 2];
    float4 bv1 = ((const float4*)bias)[tc * 2 + 1];
    #pragma unroll
    for (int rr = 0; rr < 8; rr++) {
        int row = row0 + tr * 8 + rr;
        if (row < N_NODES) {
            float4 o0, o1;
            o0.x = fmaxf(acc[rr][0] + bv0.x, 0.f);
            o0.y = fmaxf(acc[rr][1] + bv0.y, 0.f);
            o0.z = fmaxf(acc[rr][2] + bv0.z, 0.f);
            o0.w = fmaxf(acc[rr][3] + bv0.w, 0.f);
            o1.x = fmaxf(acc[rr][4] + bv1.x, 0.f);
            o1.y = fmaxf(acc[rr][5] + bv1.y, 0.f);
            o1.z = fmaxf(acc[rr][6] + bv1.z, 0.f);
            o1.w = fmaxf(acc[rr][7] + bv1.w, 0.f);
            if (MODE == 0) {
                int od = odeg[row];
                float s = 1.0f / sqrtf((float)(od > 1 ? od : 1));
                o0.x *= s; o0.y *= s; o0.z *= s; o0.w *= s;
                o1.x *= s; o1.y *= s; o1.z *= s; o1.w *= s;
                int p = tc >> 1;
                int q0 = (tc & 1) * 2;
                ((float4*)out)[p * PLANE_F4 + row * 4 + q0] = o0;
                ((float4*)out)[p * PLANE_F4 + row * 4 + q0 + 1] = o1;
            } else {
                ((float4*)out)[row * 32 + tc * 2] = o0;
                ((float4*)out)[row * 32 + tc * 2 + 1] = o1;
            }
        }
    }
}

// ---------------------------------------------------------------------------
// 8) Fused projection + readout (unchanged).
// ---------------------------------------------------------------------------
__global__ __launch_bounds__(256) void proj_readout_k(const float* __restrict__ h,
                                                      const int* __restrict__ gid,
                                                      const float* __restrict__ Wm,
                                                      float* __restrict__ hgp,
                                                      int* __restrict__ gcnt) {
    __shared__ float Wmt[10 * 144];
    int tid = threadIdx.x;
    for (int i = tid; i < 1280; i += 256) {
        int k = i / 10, o = i % 10;
        Wmt[o * 144 + k + 4 * (k >> 5)] = Wm[i];
    }
    __syncthreads();

    int v = blockIdx.x * 64 + (tid >> 2);
    int quarter = tid & 3;
    int lane = tid & 63;

    float acc[D_OUT];
    #pragma unroll
    for (int o = 0; o < D_OUT; o++) acc[o] = 0.f;
    int g = -1;
    int cnt = 0;
    if (v < N_NODES) {
        g = gid[v];
        cnt = (quarter == 0) ? 1 : 0;
        const float4* h4 = (const float4*)h + v * 32 + quarter * 8;
        const float* wbase = Wmt + quarter * 36;
        #pragma unroll
        for (int kk = 0; kk < 8; kk++) {
            float4 hv = h4[kk];
            #pragma unroll
            for (int o = 0; o < D_OUT; o++) {
                float4 w = *(const float4*)(wbase + o * 144 + kk * 4);
                acc[o] += hv.x * w.x + hv.y * w.y + hv.z * w.z + hv.w * w.w;
            }
        }
    }

    #pragma unroll
    for (int d = 1; d < 64; d <<= 1) {
        int gp = __shfl_up(g, d, 64);
        int cp = __shfl_up(cnt, d, 64);
        bool take = (lane >= d) && (gp == g);
        #pragma unroll
        for (int o = 0; o < D_OUT; o++) {
            float ap = __shfl_up(acc[o], d, 64);
            if (take) acc[o] += ap;
        }
        if (take) cnt += cp;
    }
    int gn = __shfl_down(g, 1, 64);
    bool tail = (lane == 63) || (gn != g);
    if (tail && g >= 0) {
        #pragma unroll
        for (int o = 0; o < D_OUT; o++) atomicAdd(&hgp[g * D_OUT + o], acc[o]);
        if (cnt > 0) atomicAdd(&gcnt[g], cnt);
    }
}

// ---------------------------------------------------------------------------
// 9) Final: logits = hgp/cnt + bm ; log_softmax over axis 0 (graphs)
// ---------------------------------------------------------------------------
__global__ __launch_bounds__(512) void final_k(const float* __restrict__ hgp,
                                               const int* __restrict__ gcnt,
                                               const float* __restrict__ bm,
                                               float* __restrict__ out) {
    __shared__ float lg[N_GRAPHS * D_OUT];
    __shared__ float colm[D_OUT], colls[D_OUT];
    int tid = threadIdx.x;
    if (tid < N_GRAPHS * D_OUT) {
        int g = tid / D_OUT, o = tid % D_OUT;
        float c = (float)gcnt[g];
        lg[tid] = hgp[tid] / (c > 1.f ? c : 1.f) + bm[o];
    }
    __syncthreads();
    if (tid < D_OUT) {
        float m = -1e30f;
        for (int g = 0; g < N_GRAPHS; g++) m = fmaxf(m, lg[g * D_OUT + tid]);
        float s = 0.f;
        for (int g = 0; g < N_GRAPHS; g++) s += expf(lg[g * D_OUT + tid] - m);
        colm[tid] = m; colls[tid] = logf(s);
    }
    __syncthreads();
    if (tid < N_GRAPHS * D_OUT) {
        int o = tid % D_OUT;
        out[tid] = lg[tid] - colm[o] - colls[o];
    }
}

// ---------------------------------------------------------------------------
// Launch. packed[] aliases bufB head (dead before spmm#1 writes bufB).
// Total footprint 53,556,128 B.
// ---------------------------------------------------------------------------
extern "C" void kernel_launch(void* const* d_in, const int* in_sizes, int n_in,
                              void* d_out, int out_size, void* d_ws, size_t ws_size,
                              hipStream_t stream) {
    const float* h_in = (const float*)d_in[0];
    const int*   src  = (const int*)d_in[1];
    const int*   dst  = (const int*)d_in[2];
    const int*   gid  = (const int*)d_in[3];
    const float* W1 = (const float*)d_in[4];  const float* b1 = (const float*)d_in[5];
    const float* W2 = (const float*)d_in[6];  const float* b2 = (const float*)d_in[7];
    const float* W3 = (const float*)d_in[8];  const float* b3 = (const float*)d_in[9];
    const float* Wm = (const float*)d_in[10]; const float* bm = (const float*)d_in[11];

    char* ws = (char*)d_ws;
    int*            row_ptr = (int*)(ws + 0);                     // 50001 ints (pad 200,032)
    unsigned short* col16   = (unsigned short*)(ws + 200032);     // 1,600,000 B
    float*          nd      = (float*)(ws + 1800032);             // 200,000 B
    int*            out_deg = (int*)(ws + 2000032);               // 200,000 B  } zeroed
    int*            gcnt    = (int*)(ws + 2200032);               // 256 B      } together
    float*          hgp     = (float*)(ws + 2200288);             // 2,048 B    } 202,432 B
    int*            gh      = (int*)(ws + 2202464);               // 153,664 B
    float*          bufA    = (float*)(ws + 2356128);             // 25.6 MB
    float*          bufB    = (float*)(ws + 27956128);            // 25.6 MB -> 53,556,128
    unsigned int*   packed  = (unsigned int*)bufB;                // 3.2 MB alias

    hipMemsetAsync(out_deg, 0, 202432, stream);     // out_deg+gcnt+hgp

    part_hist<<<NBLK, 256, 0, stream>>>(dst, gh);
    part_scan<<<1, 1024, 0, stream>>>(gh);
    part_scatter<<<NBLK, 256, 0, stream>>>(src, dst, gh, packed, out_deg);
    bucket_csr<<<NB, 256, 0, stream>>>(packed, gh, col16, row_ptr, nd);
    prescale_k<<<6250, 256, 0, stream>>>(h_in, out_deg, bufA);

    spmm_k<<<6256, 256, 0, stream>>>(bufA, row_ptr, col16, nd, bufB);
    gemm_relu_k<0><<<196, 512, 0, stream>>>(bufB, W1, b1, out_deg, bufA);
    spmm_k<<<6256, 256, 0, stream>>>(bufA, row_ptr, col16, nd, bufB);
    gemm_relu_k<0><<<196, 512, 0, stream>>>(bufB, W2, b2, out_deg, bufA);
    spmm_k<<<6256, 256, 0, stream>>>(bufA, row_ptr, col16, nd, bufB);
    gemm_relu_k<1><<<196, 512, 0, stream>>>(bufB, W3, b3, out_deg, bufA);

    proj_readout_k<<<782, 256, 0, stream>>>(bufA, gid, Wm, hgp, gcnt);
    final_k<<<1, 512, 0, stream>>>(hgp, gcnt, bm, (float*)d_out);
}

// Round 7
// 470.172 us; speedup vs baseline: 1.4511x; 1.1095x over previous
//
#include <hip/hip_runtime.h>

#define N_NODES 50000
#define N_EDGES 800000
#define N_GRAPHS 50
#define D 128
#define D_OUT 10
#define PLANE_F4 200000   // per-slice plane: 50000 nodes * 4 float4 (16 floats)
#define NB 196            // coarse buckets: dst>>8 (49999>>8 == 195)
#define NBLK 196          // partition blocks (196*4096 >= 800000)

// ---------------------------------------------------------------------------
// 1) Coarse partition histogram for dst (LDS atomics only). The src
//    out-degree atomics live in part_scatter (overlap the vector pipes).
// ---------------------------------------------------------------------------
__global__ __launch_bounds__(256) void part_hist(const int* __restrict__ dst,
                                                 int* __restrict__ gh) {
    __shared__ int lh[NB];
    int tid = threadIdx.x, blk = blockIdx.x;
    if (tid < NB) lh[tid] = 0;
    __syncthreads();
    int base = blk * 4096;
    #pragma unroll
    for (int j = 0; j < 16; j++) {
        int i = base + j * 256 + tid;
        if (i < N_EDGES) atomicAdd(&lh[dst[i] >> 8], 1);     // LDS atomic
    }
    __syncthreads();
    if (tid < NB) gh[tid * NBLK + blk] = lh[tid];
}

// ---------------------------------------------------------------------------
// 2) Exclusive scan of gh[NB*NBLK = 38416]: ROUND-3 CHUNKED VERSION, exact
//    revert. Coalesced (thread t loads base+t*4..+3: contiguous 16B/lane).
//    Round-6 lesson: the "one-pass" variant (38 contiguous elems/thread,
//    lanes 152B apart) was UNcoalesced on a single CU -> 65us (vs ~12us).
// ---------------------------------------------------------------------------
__global__ __launch_bounds__(1024) void part_scan(int* __restrict__ gh) {
    __shared__ int wsum[16];
    __shared__ int carry_s;
    const int N = NB * NBLK;            // 38416
    int tid = threadIdx.x;
    int lane = tid & 63, wid = tid >> 6;
    if (tid == 0) carry_s = 0;
    __syncthreads();
    for (int base = 0; base < N; base += 4096) {
        int i0 = base + tid * 4;
        int v0 = (i0 + 0 < N) ? gh[i0 + 0] : 0;
        int v1 = (i0 + 1 < N) ? gh[i0 + 1] : 0;
        int v2 = (i0 + 2 < N) ? gh[i0 + 2] : 0;
        int v3 = (i0 + 3 < N) ? gh[i0 + 3] : 0;
        int s = v0 + v1 + v2 + v3;
        int x = s;
        #pragma unroll
        for (int d = 1; d < 64; d <<= 1) {
            int y = __shfl_up(x, d, 64);
            if (lane >= d) x += y;
        }
        if (lane == 63) wsum[wid] = x;
        __syncthreads();
        if (wid == 0) {
            int t = (lane < 16) ? wsum[lane] : 0;
            #pragma unroll
            for (int d = 1; d < 16; d <<= 1) {
                int y = __shfl_up(t, d, 64);
                if (lane >= d) t += y;
            }
            if (lane < 16) wsum[lane] = t;
        }
        __syncthreads();
        int woff = (wid == 0) ? 0 : wsum[wid - 1];
        int run = carry_s + woff + (x - s);
        if (i0 + 0 < N) gh[i0 + 0] = run; run += v0;
        if (i0 + 1 < N) gh[i0 + 1] = run; run += v1;
        if (i0 + 2 < N) gh[i0 + 2] = run; run += v2;
        if (i0 + 3 < N) gh[i0 + 3] = run; run += v3;
        __syncthreads();
        if (tid == 0) carry_s += wsum[15];
        __syncthreads();
    }
}

// ---------------------------------------------------------------------------
// 3) Partition scatter (LDS cursors) + src out-degree histogram riding the
//    otherwise-idle device-atomic pipe.
// ---------------------------------------------------------------------------
__global__ __launch_bounds__(256) void part_scatter(const int* __restrict__ src,
                                                    const int* __restrict__ dst,
                                                    const int* __restrict__ gh,
                                                    unsigned int* __restrict__ packed,
                                                    int* __restrict__ out_deg) {
    __shared__ int lc[NB];
    int tid = threadIdx.x, blk = blockIdx.x;
    if (tid < NB) lc[tid] = gh[tid * NBLK + blk];
    __syncthreads();
    int base = blk * 4096;
    #pragma unroll
    for (int j = 0; j < 16; j++) {
        int i = base + j * 256 + tid;
        if (i < N_EDGES) {
            int d = dst[i];
            int s = src[i];
            atomicAdd(&out_deg[s], 1);               // device atomic (src stream)
            int p = atomicAdd(&lc[d >> 8], 1);       // LDS atomic
            packed[p] = ((unsigned int)(d & 255) << 16) | (unsigned int)s;
        }
    }
}

// ---------------------------------------------------------------------------
// 4) Per-bucket CSR build: one block per coarse bucket (~4096 edges, <=8192).
//    LDS-staged: 256-bin hist -> block scan -> row_ptr + nd + coalesced col16.
// ---------------------------------------------------------------------------
__global__ __launch_bounds__(256) void bucket_csr(const unsigned int* __restrict__ packed,
                                                  const int* __restrict__ gh,
                                                  unsigned short* __restrict__ col16,
                                                  int* __restrict__ row_ptr,
                                                  float* __restrict__ nd) {
    __shared__ unsigned int ep[8192];
    __shared__ unsigned short lcol[8192];
    __shared__ int hist[256], cur[256], wsum[4];
    int t = threadIdx.x, b = blockIdx.x;
    int nb = gh[b * NBLK];
    int ne = (b < NB - 1) ? gh[(b + 1) * NBLK] : N_EDGES;
    int cnt = ne - nb;
    if (cnt > 8192) cnt = 8192;         // statistically unreachable guard
    hist[t] = 0;
    __syncthreads();
    for (int i = t; i < cnt; i += 256) {
        unsigned int e = packed[nb + i];
        ep[i] = e;
        atomicAdd(&hist[e >> 16], 1);
    }
    __syncthreads();
    int v = hist[t];
    int lane = t & 63, w = t >> 6;
    int x = v;
    #pragma unroll
    for (int d = 1; d < 64; d <<= 1) {
        int y = __shfl_up(x, d, 64);
        if (lane >= d) x += y;
    }
    if (lane == 63) wsum[w] = x;
    __syncthreads();
    int add = 0;
    #pragma unroll
    for (int i = 0; i < 4; i++) if (i < w) add += wsum[i];
    int excl = add + x - v;
    cur[t] = excl;
    int node = b * 256 + t;
    if (node < N_NODES) {
        row_ptr[node] = nb + excl;
        int id = v > 1 ? v : 1;
        nd[node] = 1.0f / sqrtf((float)id);
    }
    if (b == NB - 1 && t == 0) row_ptr[N_NODES] = N_EDGES;
    __syncthreads();
    for (int i = t; i < cnt; i += 256) {
        unsigned int e = ep[i];
        int p = atomicAdd(&cur[e >> 16], 1);         // LDS atomic
        lcol[p] = (unsigned short)(e & 0xFFFF);
    }
    __syncthreads();
    for (int i = t; i < cnt; i += 256) col16[nb + i] = lcol[i];
}

// ---------------------------------------------------------------------------
// 5) Prescale + slice: xs[p][node][16] = out_deg[node]^-1/2 * h[node][p*16..].
// ---------------------------------------------------------------------------
__global__ __launch_bounds__(256) void prescale_k(const float* __restrict__ h,
                                                  const int* __restrict__ out_deg,
                                                  float* __restrict__ out) {
    int i = blockIdx.x * 256 + threadIdx.x;      // over 1,600,000 float4s
    if (i < N_NODES * 32) {
        int node = i >> 5;
        int kg = i & 31;
        float4 v = ((const float4*)h)[i];
        int od = out_deg[node];
        float s = 1.0f / sqrtf((float)(od > 1 ? od : 1));
        int p = kg >> 2, q = kg & 3;
        ((float4*)out)[p * PLANE_F4 + node * 4 + q] =
            make_float4(v.x * s, v.y * s, v.z * s, v.w * s);
    }
}

// ---------------------------------------------------------------------------
// 6) Feature-sliced SpMM -- round-3 exact shape (twice-measured 54.4us,
//    FETCH 23.8MB at grid 6256, 256-thread blocks, slice=b&7, 64 nodes/blk).
//    Do NOT change grid/block/slice mapping without re-measuring FETCH_SIZE
//    (r4: grid 1568 -> 187MB; r5: XCC_ID queue -> 188MB).
// ---------------------------------------------------------------------------
__global__ __launch_bounds__(256) void spmm_k(const float* __restrict__ x,   // sliced
                                              const int* __restrict__ row_ptr,
                                              const unsigned short* __restrict__ col,
                                              const float* __restrict__ nd,
                                              float* __restrict__ out) {     // sliced
    int b = blockIdx.x;
    int slice = b & 7;
    int node = (b >> 3) * 64 + (threadIdx.x >> 2);
    if (node >= N_NODES) return;
    int q = threadIdx.x & 3;
    int s = row_ptr[node];
    int e = row_ptr[node + 1];
    const float4* xp = (const float4*)x + slice * PLANE_F4;
    float4 a0 = make_float4(0.f, 0.f, 0.f, 0.f);
    float4 a1 = make_float4(0.f, 0.f, 0.f, 0.f);
    int i = s;
    for (; i + 4 <= e; i += 4) {
        int c0 = col[i], c1 = col[i + 1], c2 = col[i + 2], c3 = col[i + 3];
        float4 h0 = xp[c0 * 4 + q];
        float4 h1 = xp[c1 * 4 + q];
        float4 h2 = xp[c2 * 4 + q];
        float4 h3 = xp[c3 * 4 + q];
        a0.x += h0.x; a0.y += h0.y; a0.z += h0.z; a0.w += h0.w;
        a1.x += h1.x; a1.y += h1.y; a1.z += h1.z; a1.w += h1.w;
        a0.x += h2.x; a0.y += h2.y; a0.z += h2.z; a0.w += h2.w;
        a1.x += h3.x; a1.y += h3.y; a1.z += h3.z; a1.w += h3.w;
    }
    for (; i < e; i++) {
        float4 hv = xp[col[i] * 4 + q];
        a0.x += hv.x; a0.y += hv.y; a0.z += hv.z; a0.w += hv.w;
    }
    float ndv = nd[node];
    ((float4*)out)[slice * PLANE_F4 + node * 4 + q] =
        make_float4((a0.x + a1.x) * ndv, (a0.y + a1.y) * ndv,
                    (a0.z + a1.z) * ndv, (a0.w + a1.w) * ndv);
}

// ---------------------------------------------------------------------------
// 7) GEMM + bias + ReLU (known-good shape).
//    MODE 0: out = odeg^-1/2 * relu(A@W+b), SLICED. MODE 1: normal layout.
// ---------------------------------------------------------------------------
template <int MODE>
__global__ __launch_bounds__(512) void gemm_relu_k(const float* __restrict__ A,  // sliced
                                                   const float* __restrict__ W,
                                                   const float* __restrict__ bias,
                                                   const int* __restrict__ odeg,
                                                   float* __restrict__ out) {
    __shared__ float As_t[128 * 256];   // 128 KB: [k][r]
    int tid = threadIdx.x;
    int row0 = blockIdx.x * 256;
    const float4* A4 = (const float4*)A;

    #pragma unroll
    for (int it = 0; it < 16; it++) {
        int linear = it * 512 + tid;       // 0..8191 float4s
        int p = linear >> 10;              // plane 0..7
        int rem = linear & 1023;
        int r = rem >> 2;                  // local row 0..255
        int q = rem & 3;                   // float4 within 16-float slice
        int row = row0 + r;
        float4 a = (row < N_NODES) ? A4[p * PLANE_F4 + row * 4 + q]
                                   : make_float4(0.f, 0.f, 0.f, 0.f);
        int kb = p * 16 + q * 4;
        As_t[(kb + 0) * 256 + r] = a.x;
        As_t[(kb + 1) * 256 + r] = a.y;
        As_t[(kb + 2) * 256 + r] = a.z;
        As_t[(kb + 3) * 256 + r] = a.w;
    }
    __syncthreads();

    int tc = tid & 15;    // col group: cols tc*8 .. +8
    int tr = tid >> 4;    // 0..31 : rows tr*8 .. +8
    float acc[8][8];
    #pragma unroll
    for (int r = 0; r < 8; r++)
        #pragma unroll
        for (int c = 0; c < 8; c++) acc[r][c] = 0.f;

    const float4* W4 = (const float4*)W;
    #pragma unroll 2
    for (int k = 0; k < 128; k++) {
        float4 w0 = W4[k * 32 + tc * 2];
        float4 w1 = W4[k * 32 + tc * 2 + 1];
        float4 a0 = *(const float4*)(As_t + k * 256 + tr * 8);
        float4 a1 = *(const float4*)(As_t + k * 256 + tr * 8 + 4);
        float av[8] = {a0.x, a0.y, a0.z, a0.w, a1.x, a1.y, a1.z, a1.w};
        float wv[8] = {w0.x, w0.y, w0.z, w0.w, w1.x, w1.y, w1.z, w1.w};
        #pragma unroll
        for (int rr = 0; rr < 8; rr++)
            #pragma unroll
            for (int cc = 0; cc < 8; cc++)
                acc[rr][cc] = fmaf(av[rr], wv[cc], acc[rr][cc]);
    }

    float4 bv0 = ((const float4*)bias)[tc * 2];
    float4 bv1 = ((const float4*)bias)[tc * 2 + 1];
    #pragma unroll
    for (int rr = 0; rr < 8; rr++) {
        int row = row0 + tr * 8 + rr;
        if (row < N_NODES) {
            float4 o0, o1;
            o0.x = fmaxf(acc[rr][0] + bv0.x, 0.f);
            o0.y = fmaxf(acc[rr][1] + bv0.y, 0.f);
            o0.z = fmaxf(acc[rr][2] + bv0.z, 0.f);
            o0.w = fmaxf(acc[rr][3] + bv0.w, 0.f);
            o1.x = fmaxf(acc[rr][4] + bv1.x, 0.f);
            o1.y = fmaxf(acc[rr][5] + bv1.y, 0.f);
            o1.z = fmaxf(acc[rr][6] + bv1.z, 0.f);
            o1.w = fmaxf(acc[rr][7] + bv1.w, 0.f);
            if (MODE == 0) {
                int od = odeg[row];
                float s = 1.0f / sqrtf((float)(od > 1 ? od : 1));
                o0.x *= s; o0.y *= s; o0.z *= s; o0.w *= s;
                o1.x *= s; o1.y *= s; o1.z *= s; o1.w *= s;
                int p = tc >> 1;
                int q0 = (tc & 1) * 2;
                ((float4*)out)[p * PLANE_F4 + row * 4 + q0] = o0;
                ((float4*)out)[p * PLANE_F4 + row * 4 + q0 + 1] = o1;
            } else {
                ((float4*)out)[row * 32 + tc * 2] = o0;
                ((float4*)out)[row * 32 + tc * 2 + 1] = o1;
            }
        }
    }
}

// ---------------------------------------------------------------------------
// 8) Fused projection + readout (unchanged).
// ---------------------------------------------------------------------------
__global__ __launch_bounds__(256) void proj_readout_k(const float* __restrict__ h,
                                                      const int* __restrict__ gid,
                                                      const float* __restrict__ Wm,
                                                      float* __restrict__ hgp,
                                                      int* __restrict__ gcnt) {
    __shared__ float Wmt[10 * 144];
    int tid = threadIdx.x;
    for (int i = tid; i < 1280; i += 256) {
        int k = i / 10, o = i % 10;
        Wmt[o * 144 + k + 4 * (k >> 5)] = Wm[i];
    }
    __syncthreads();

    int v = blockIdx.x * 64 + (tid >> 2);
    int quarter = tid & 3;
    int lane = tid & 63;

    float acc[D_OUT];
    #pragma unroll
    for (int o = 0; o < D_OUT; o++) acc[o] = 0.f;
    int g = -1;
    int cnt = 0;
    if (v < N_NODES) {
        g = gid[v];
        cnt = (quarter == 0) ? 1 : 0;
        const float4* h4 = (const float4*)h + v * 32 + quarter * 8;
        const float* wbase = Wmt + quarter * 36;
        #pragma unroll
        for (int kk = 0; kk < 8; kk++) {
            float4 hv = h4[kk];
            #pragma unroll
            for (int o = 0; o < D_OUT; o++) {
                float4 w = *(const float4*)(wbase + o * 144 + kk * 4);
                acc[o] += hv.x * w.x + hv.y * w.y + hv.z * w.z + hv.w * w.w;
            }
        }
    }

    #pragma unroll
    for (int d = 1; d < 64; d <<= 1) {
        int gp = __shfl_up(g, d, 64);
        int cp = __shfl_up(cnt, d, 64);
        bool take = (lane >= d) && (gp == g);
        #pragma unroll
        for (int o = 0; o < D_OUT; o++) {
            float ap = __shfl_up(acc[o], d, 64);
            if (take) acc[o] += ap;
        }
        if (take) cnt += cp;
    }
    int gn = __shfl_down(g, 1, 64);
    bool tail = (lane == 63) || (gn != g);
    if (tail && g >= 0) {
        #pragma unroll
        for (int o = 0; o < D_OUT; o++) atomicAdd(&hgp[g * D_OUT + o], acc[o]);
        if (cnt > 0) atomicAdd(&gcnt[g], cnt);
    }
}

// ---------------------------------------------------------------------------
// 9) Final: logits = hgp/cnt + bm ; log_softmax over axis 0 (graphs)
// ---------------------------------------------------------------------------
__global__ __launch_bounds__(512) void final_k(const float* __restrict__ hgp,
                                               const int* __restrict__ gcnt,
                                               const float* __restrict__ bm,
                                               float* __restrict__ out) {
    __shared__ float lg[N_GRAPHS * D_OUT];
    __shared__ float colm[D_OUT], colls[D_OUT];
    int tid = threadIdx.x;
    if (tid < N_GRAPHS * D_OUT) {
        int g = tid / D_OUT, o = tid % D_OUT;
        float c = (float)gcnt[g];
        lg[tid] = hgp[tid] / (c > 1.f ? c : 1.f) + bm[o];
    }
    __syncthreads();
    if (tid < D_OUT) {
        float m = -1e30f;
        for (int g = 0; g < N_GRAPHS; g++) m = fmaxf(m, lg[g * D_OUT + tid]);
        float s = 0.f;
        for (int g = 0; g < N_GRAPHS; g++) s += expf(lg[g * D_OUT + tid] - m);
        colm[tid] = m; colls[tid] = logf(s);
    }
    __syncthreads();
    if (tid < N_GRAPHS * D_OUT) {
        int o = tid % D_OUT;
        out[tid] = lg[tid] - colm[o] - colls[o];
    }
}

// ---------------------------------------------------------------------------
// Launch. packed[] aliases bufB head (dead before spmm#1 writes bufB).
// Total footprint 53,556,128 B.
// ---------------------------------------------------------------------------
extern "C" void kernel_launch(void* const* d_in, const int* in_sizes, int n_in,
                              void* d_out, int out_size, void* d_ws, size_t ws_size,
                              hipStream_t stream) {
    const float* h_in = (const float*)d_in[0];
    const int*   src  = (const int*)d_in[1];
    const int*   dst  = (const int*)d_in[2];
    const int*   gid  = (const int*)d_in[3];
    const float* W1 = (const float*)d_in[4];  const float* b1 = (const float*)d_in[5];
    const float* W2 = (const float*)d_in[6];  const float* b2 = (const float*)d_in[7];
    const float* W3 = (const float*)d_in[8];  const float* b3 = (const float*)d_in[9];
    const float* Wm = (const float*)d_in[10]; const float* bm = (const float*)d_in[11];

    char* ws = (char*)d_ws;
    int*            row_ptr = (int*)(ws + 0);                     // 50001 ints (pad 200,032)
    unsigned short* col16   = (unsigned short*)(ws + 200032);     // 1,600,000 B
    float*          nd      = (float*)(ws + 1800032);             // 200,000 B
    int*            out_deg = (int*)(ws + 2000032);               // 200,000 B  } zeroed
    int*            gcnt    = (int*)(ws + 2200032);               // 256 B      } together
    float*          hgp     = (float*)(ws + 2200288);             // 2,048 B    } 202,432 B
    int*            gh      = (int*)(ws + 2202464);               // 153,664 B
    float*          bufA    = (float*)(ws + 2356128);             // 25.6 MB
    float*          bufB    = (float*)(ws + 27956128);            // 25.6 MB -> 53,556,128
    unsigned int*   packed  = (unsigned int*)bufB;                // 3.2 MB alias

    hipMemsetAsync(out_deg, 0, 202432, stream);     // out_deg+gcnt+hgp

    part_hist<<<NBLK, 256, 0, stream>>>(dst, gh);
    part_scan<<<1, 1024, 0, stream>>>(gh);
    part_scatter<<<NBLK, 256, 0, stream>>>(src, dst, gh, packed, out_deg);
    bucket_csr<<<NB, 256, 0, stream>>>(packed, gh, col16, row_ptr, nd);
    prescale_k<<<6250, 256, 0, stream>>>(h_in, out_deg, bufA);

    spmm_k<<<6256, 256, 0, stream>>>(bufA, row_ptr, col16, nd, bufB);
    gemm_relu_k<0><<<196, 512, 0, stream>>>(bufB, W1, b1, out_deg, bufA);
    spmm_k<<<6256, 256, 0, stream>>>(bufA, row_ptr, col16, nd, bufB);
    gemm_relu_k<0><<<196, 512, 0, stream>>>(bufB, W2, b2, out_deg, bufA);
    spmm_k<<<6256, 256, 0, stream>>>(bufA, row_ptr, col16, nd, bufB);
    gemm_relu_k<1><<<196, 512, 0, stream>>>(bufB, W3, b3, out_deg, bufA);

    proj_readout_k<<<782, 256, 0, stream>>>(bufA, gid, Wm, hgp, gcnt);
    final_k<<<1, 512, 0, stream>>>(hgp, gcnt, bm, (float*)d_out);
}

// Round 8
// 466.962 us; speedup vs baseline: 1.4611x; 1.0069x over previous
//
#include <hip/hip_runtime.h>

#define N_NODES 50000
#define N_EDGES 800000
#define N_GRAPHS 50
#define D 128
#define D_OUT 10
#define PLANE_F4 200000   // per-slice plane: 50000 nodes * 4 float4 (16 floats)
#define NB 196            // coarse buckets: dst>>8 (49999>>8 == 195)
#define NBLK 196          // partition blocks (196*4096 >= 800000)

// ---------------------------------------------------------------------------
// 1) Coarse partition histogram for dst (LDS atomics only). The src
//    out-degree atomics live in part_scatter (overlap the vector pipes).
// ---------------------------------------------------------------------------
__global__ __launch_bounds__(256) void part_hist(const int* __restrict__ dst,
                                                 int* __restrict__ gh) {
    __shared__ int lh[NB];
    int tid = threadIdx.x, blk = blockIdx.x;
    if (tid < NB) lh[tid] = 0;
    __syncthreads();
    int base = blk * 4096;
    #pragma unroll
    for (int j = 0; j < 16; j++) {
        int i = base + j * 256 + tid;
        if (i < N_EDGES) atomicAdd(&lh[dst[i] >> 8], 1);     // LDS atomic
    }
    __syncthreads();
    if (tid < NB) gh[tid * NBLK + blk] = lh[tid];
}

// ---------------------------------------------------------------------------
// 2) Exclusive scan of gh[NB*NBLK = 38416]: round-3 chunked version
//    (coalesced: thread t loads base+t*4..+3). Round-6 lesson: the one-pass
//    contiguous-per-thread variant was uncoalesced on one CU -> 65us.
// ---------------------------------------------------------------------------
__global__ __launch_bounds__(1024) void part_scan(int* __restrict__ gh) {
    __shared__ int wsum[16];
    __shared__ int carry_s;
    const int N = NB * NBLK;            // 38416
    int tid = threadIdx.x;
    int lane = tid & 63, wid = tid >> 6;
    if (tid == 0) carry_s = 0;
    __syncthreads();
    for (int base = 0; base < N; base += 4096) {
        int i0 = base + tid * 4;
        int v0 = (i0 + 0 < N) ? gh[i0 + 0] : 0;
        int v1 = (i0 + 1 < N) ? gh[i0 + 1] : 0;
        int v2 = (i0 + 2 < N) ? gh[i0 + 2] : 0;
        int v3 = (i0 + 3 < N) ? gh[i0 + 3] : 0;
        int s = v0 + v1 + v2 + v3;
        int x = s;
        #pragma unroll
        for (int d = 1; d < 64; d <<= 1) {
            int y = __shfl_up(x, d, 64);
            if (lane >= d) x += y;
        }
        if (lane == 63) wsum[wid] = x;
        __syncthreads();
        if (wid == 0) {
            int t = (lane < 16) ? wsum[lane] : 0;
            #pragma unroll
            for (int d = 1; d < 16; d <<= 1) {
                int y = __shfl_up(t, d, 64);
                if (lane >= d) t += y;
            }
            if (lane < 16) wsum[lane] = t;
        }
        __syncthreads();
        int woff = (wid == 0) ? 0 : wsum[wid - 1];
        int run = carry_s + woff + (x - s);
        if (i0 + 0 < N) gh[i0 + 0] = run; run += v0;
        if (i0 + 1 < N) gh[i0 + 1] = run; run += v1;
        if (i0 + 2 < N) gh[i0 + 2] = run; run += v2;
        if (i0 + 3 < N) gh[i0 + 3] = run; run += v3;
        __syncthreads();
        if (tid == 0) carry_s += wsum[15];
        __syncthreads();
    }
}

// ---------------------------------------------------------------------------
// 3) Partition scatter (LDS cursors) + src out-degree histogram riding the
//    otherwise-idle device-atomic pipe.
// ---------------------------------------------------------------------------
__global__ __launch_bounds__(256) void part_scatter(const int* __restrict__ src,
                                                    const int* __restrict__ dst,
                                                    const int* __restrict__ gh,
                                                    unsigned int* __restrict__ packed,
                                                    int* __restrict__ out_deg) {
    __shared__ int lc[NB];
    int tid = threadIdx.x, blk = blockIdx.x;
    if (tid < NB) lc[tid] = gh[tid * NBLK + blk];
    __syncthreads();
    int base = blk * 4096;
    #pragma unroll
    for (int j = 0; j < 16; j++) {
        int i = base + j * 256 + tid;
        if (i < N_EDGES) {
            int d = dst[i];
            int s = src[i];
            atomicAdd(&out_deg[s], 1);               // device atomic (src stream)
            int p = atomicAdd(&lc[d >> 8], 1);       // LDS atomic
            packed[p] = ((unsigned int)(d & 255) << 16) | (unsigned int)s;
        }
    }
}

// ---------------------------------------------------------------------------
// 4) Per-bucket CSR build: one block per coarse bucket (~4096 edges, <=8192).
//    LDS-staged: 256-bin hist -> block scan -> row_ptr + nd + coalesced col16.
// ---------------------------------------------------------------------------
__global__ __launch_bounds__(256) void bucket_csr(const unsigned int* __restrict__ packed,
                                                  const int* __restrict__ gh,
                                                  unsigned short* __restrict__ col16,
                                                  int* __restrict__ row_ptr,
                                                  float* __restrict__ nd) {
    __shared__ unsigned int ep[8192];
    __shared__ unsigned short lcol[8192];
    __shared__ int hist[256], cur[256], wsum[4];
    int t = threadIdx.x, b = blockIdx.x;
    int nb = gh[b * NBLK];
    int ne = (b < NB - 1) ? gh[(b + 1) * NBLK] : N_EDGES;
    int cnt = ne - nb;
    if (cnt > 8192) cnt = 8192;         // statistically unreachable guard
    hist[t] = 0;
    __syncthreads();
    for (int i = t; i < cnt; i += 256) {
        unsigned int e = packed[nb + i];
        ep[i] = e;
        atomicAdd(&hist[e >> 16], 1);
    }
    __syncthreads();
    int v = hist[t];
    int lane = t & 63, w = t >> 6;
    int x = v;
    #pragma unroll
    for (int d = 1; d < 64; d <<= 1) {
        int y = __shfl_up(x, d, 64);
        if (lane >= d) x += y;
    }
    if (lane == 63) wsum[w] = x;
    __syncthreads();
    int add = 0;
    #pragma unroll
    for (int i = 0; i < 4; i++) if (i < w) add += wsum[i];
    int excl = add + x - v;
    cur[t] = excl;
    int node = b * 256 + t;
    if (node < N_NODES) {
        row_ptr[node] = nb + excl;
        int id = v > 1 ? v : 1;
        nd[node] = 1.0f / sqrtf((float)id);
    }
    if (b == NB - 1 && t == 0) row_ptr[N_NODES] = N_EDGES;
    __syncthreads();
    for (int i = t; i < cnt; i += 256) {
        unsigned int e = ep[i];
        int p = atomicAdd(&cur[e >> 16], 1);         // LDS atomic
        lcol[p] = (unsigned short)(e & 0xFFFF);
    }
    __syncthreads();
    for (int i = t; i < cnt; i += 256) col16[nb + i] = lcol[i];
}

// ---------------------------------------------------------------------------
// 5) Prescale + slice: xs[p][node][16] = out_deg[node]^-1/2 * h[node][p*16..].
// ---------------------------------------------------------------------------
__global__ __launch_bounds__(256) void prescale_k(const float* __restrict__ h,
                                                  const int* __restrict__ out_deg,
                                                  float* __restrict__ out) {
    int i = blockIdx.x * 256 + threadIdx.x;      // over 1,600,000 float4s
    if (i < N_NODES * 32) {
        int node = i >> 5;
        int kg = i & 31;
        float4 v = ((const float4*)h)[i];
        int od = out_deg[node];
        float s = 1.0f / sqrtf((float)(od > 1 ? od : 1));
        int p = kg >> 2, q = kg & 3;
        ((float4*)out)[p * PLANE_F4 + node * 4 + q] =
            make_float4(v.x * s, v.y * s, v.z * s, v.w * s);
    }
}

// ---------------------------------------------------------------------------
// 6) Feature-sliced SpMM. Shape LOCKED (grid 6256, 256 threads, slice=b&7,
//    64 nodes/blk, 4 lanes/node): 3x measured FETCH 23.8MB; r4/r5 shape
//    changes re-replicated to ~188MB. THIS round's single variable: edge
//    loop unroll 4->8 with 4 independent accumulators. Rationale: gathers
//    are L2-hit (~200cy); 4 outstanding/wave x ~21 waves/CU = 84 in flight
//    vs ~200 needed to saturate 1 segment/cycle -> latency-bound. 8
//    outstanding doubles MLP. Predicted 55 -> ~40us, FETCH unchanged.
// ---------------------------------------------------------------------------
__global__ __launch_bounds__(256) void spmm_k(const float* __restrict__ x,   // sliced
                                              const int* __restrict__ row_ptr,
                                              const unsigned short* __restrict__ col,
                                              const float* __restrict__ nd,
                                              float* __restrict__ out) {     // sliced
    int b = blockIdx.x;
    int slice = b & 7;
    int node = (b >> 3) * 64 + (threadIdx.x >> 2);
    if (node >= N_NODES) return;
    int q = threadIdx.x & 3;
    int s = row_ptr[node];
    int e = row_ptr[node + 1];
    const float4* xp = (const float4*)x + slice * PLANE_F4;
    float4 a0 = make_float4(0.f, 0.f, 0.f, 0.f);
    float4 a1 = make_float4(0.f, 0.f, 0.f, 0.f);
    float4 a2 = make_float4(0.f, 0.f, 0.f, 0.f);
    float4 a3 = make_float4(0.f, 0.f, 0.f, 0.f);
    int i = s;
    for (; i + 8 <= e; i += 8) {
        int c0 = col[i],     c1 = col[i + 1], c2 = col[i + 2], c3 = col[i + 3];
        int c4 = col[i + 4], c5 = col[i + 5], c6 = col[i + 6], c7 = col[i + 7];
        float4 h0 = xp[c0 * 4 + q];
        float4 h1 = xp[c1 * 4 + q];
        float4 h2 = xp[c2 * 4 + q];
        float4 h3 = xp[c3 * 4 + q];
        float4 h4 = xp[c4 * 4 + q];
        float4 h5 = xp[c5 * 4 + q];
        float4 h6 = xp[c6 * 4 + q];
        float4 h7 = xp[c7 * 4 + q];
        a0.x += h0.x; a0.y += h0.y; a0.z += h0.z; a0.w += h0.w;
        a1.x += h1.x; a1.y += h1.y; a1.z += h1.z; a1.w += h1.w;
        a2.x += h2.x; a2.y += h2.y; a2.z += h2.z; a2.w += h2.w;
        a3.x += h3.x; a3.y += h3.y; a3.z += h3.z; a3.w += h3.w;
        a0.x += h4.x; a0.y += h4.y; a0.z += h4.z; a0.w += h4.w;
        a1.x += h5.x; a1.y += h5.y; a1.z += h5.z; a1.w += h5.w;
        a2.x += h6.x; a2.y += h6.y; a2.z += h6.z; a2.w += h6.w;
        a3.x += h7.x; a3.y += h7.y; a3.z += h7.z; a3.w += h7.w;
    }
    for (; i + 4 <= e; i += 4) {
        int c0 = col[i], c1 = col[i + 1], c2 = col[i + 2], c3 = col[i + 3];
        float4 h0 = xp[c0 * 4 + q];
        float4 h1 = xp[c1 * 4 + q];
        float4 h2 = xp[c2 * 4 + q];
        float4 h3 = xp[c3 * 4 + q];
        a0.x += h0.x; a0.y += h0.y; a0.z += h0.z; a0.w += h0.w;
        a1.x += h1.x; a1.y += h1.y; a1.z += h1.z; a1.w += h1.w;
        a2.x += h2.x; a2.y += h2.y; a2.z += h2.z; a2.w += h2.w;
        a3.x += h3.x; a3.y += h3.y; a3.z += h3.z; a3.w += h3.w;
    }
    for (; i < e; i++) {
        float4 hv = xp[col[i] * 4 + q];
        a0.x += hv.x; a0.y += hv.y; a0.z += hv.z; a0.w += hv.w;
    }
    float ndv = nd[node];
    ((float4*)out)[slice * PLANE_F4 + node * 4 + q] =
        make_float4((a0.x + a1.x + a2.x + a3.x) * ndv,
                    (a0.y + a1.y + a2.y + a3.y) * ndv,
                    (a0.z + a1.z + a2.z + a3.z) * ndv,
                    (a0.w + a1.w + a2.w + a3.w) * ndv);
}

// ---------------------------------------------------------------------------
// 7) GEMM + bias + ReLU (known-good shape, unchanged).
//    MODE 0: out = odeg^-1/2 * relu(A@W+b), SLICED. MODE 1: normal layout.
// ---------------------------------------------------------------------------
template <int MODE>
__global__ __launch_bounds__(512) void gemm_relu_k(const float* __restrict__ A,  // sliced
                                                   const float* __restrict__ W,
                                                   const float* __restrict__ bias,
                                                   const int* __restrict__ odeg,
                                                   float* __restrict__ out) {
    __shared__ float As_t[128 * 256];   // 128 KB: [k][r]
    int tid = threadIdx.x;
    int row0 = blockIdx.x * 256;
    const float4* A4 = (const float4*)A;

    #pragma unroll
    for (int it = 0; it < 16; it++) {
        int linear = it * 512 + tid;       // 0..8191 float4s
        int p = linear >> 10;              // plane 0..7
        int rem = linear & 1023;
        int r = rem >> 2;                  // local row 0..255
        int q = rem & 3;                   // float4 within 16-float slice
        int row = row0 + r;
        float4 a = (row < N_NODES) ? A4[p * PLANE_F4 + row * 4 + q]
                                   : make_float4(0.f, 0.f, 0.f, 0.f);
        int kb = p * 16 + q * 4;
        As_t[(kb + 0) * 256 + r] = a.x;
        As_t[(kb + 1) * 256 + r] = a.y;
        As_t[(kb + 2) * 256 + r] = a.z;
        As_t[(kb + 3) * 256 + r] = a.w;
    }
    __syncthreads();

    int tc = tid & 15;    // col group: cols tc*8 .. +8
    int tr = tid >> 4;    // 0..31 : rows tr*8 .. +8
    float acc[8][8];
    #pragma unroll
    for (int r = 0; r < 8; r++)
        #pragma unroll
        for (int c = 0; c < 8; c++) acc[r][c] = 0.f;

    const float4* W4 = (const float4*)W;
    #pragma unroll 2
    for (int k = 0; k < 128; k++) {
        float4 w0 = W4[k * 32 + tc * 2];
        float4 w1 = W4[k * 32 + tc * 2 + 1];
        float4 a0 = *(const float4*)(As_t + k * 256 + tr * 8);
        float4 a1 = *(const float4*)(As_t + k * 256 + tr * 8 + 4);
        float av[8] = {a0.x, a0.y, a0.z, a0.w, a1.x, a1.y, a1.z, a1.w};
        float wv[8] = {w0.x, w0.y, w0.z, w0.w, w1.x, w1.y, w1.z, w1.w};
        #pragma unroll
        for (int rr = 0; rr < 8; rr++)
            #pragma unroll
            for (int cc = 0; cc < 8; cc++)
                acc[rr][cc] = fmaf(av[rr], wv[cc], acc[rr][cc]);
    }

    float4 bv0 = ((const float4*)bias)[tc * 2];
    float4 bv1 = ((const float4*)bias)[tc * 2 + 1];
    #pragma unroll
    for (int rr = 0; rr < 8; rr++) {
        int row = row0 + tr * 8 + rr;
        if (row < N_NODES) {
            float4 o0, o1;
            o0.x = fmaxf(acc[rr][0] + bv0.x, 0.f);
            o0.y = fmaxf(acc[rr][1] + bv0.y, 0.f);
            o0.z = fmaxf(acc[rr][2] + bv0.z, 0.f);
            o0.w = fmaxf(acc[rr][3] + bv0.w, 0.f);
            o1.x = fmaxf(acc[rr][4] + bv1.x, 0.f);
            o1.y = fmaxf(acc[rr][5] + bv1.y, 0.f);
            o1.z = fmaxf(acc[rr][6] + bv1.z, 0.f);
            o1.w = fmaxf(acc[rr][7] + bv1.w, 0.f);
            if (MODE == 0) {
                int od = odeg[row];
                float s = 1.0f / sqrtf((float)(od > 1 ? od : 1));
                o0.x *= s; o0.y *= s; o0.z *= s; o0.w *= s;
                o1.x *= s; o1.y *= s; o1.z *= s; o1.w *= s;
                int p = tc >> 1;
                int q0 = (tc & 1) * 2;
                ((float4*)out)[p * PLANE_F4 + row * 4 + q0] = o0;
                ((float4*)out)[p * PLANE_F4 + row * 4 + q0 + 1] = o1;
            } else {
                ((float4*)out)[row * 32 + tc * 2] = o0;
                ((float4*)out)[row * 32 + tc * 2 + 1] = o1;
            }
        }
    }
}

// ---------------------------------------------------------------------------
// 8) Fused projection + readout (unchanged).
// ---------------------------------------------------------------------------
__global__ __launch_bounds__(256) void proj_readout_k(const float* __restrict__ h,
                                                      const int* __restrict__ gid,
                                                      const float* __restrict__ Wm,
                                                      float* __restrict__ hgp,
                                                      int* __restrict__ gcnt) {
    __shared__ float Wmt[10 * 144];
    int tid = threadIdx.x;
    for (int i = tid; i < 1280; i += 256) {
        int k = i / 10, o = i % 10;
        Wmt[o * 144 + k + 4 * (k >> 5)] = Wm[i];
    }
    __syncthreads();

    int v = blockIdx.x * 64 + (tid >> 2);
    int quarter = tid & 3;
    int lane = tid & 63;

    float acc[D_OUT];
    #pragma unroll
    for (int o = 0; o < D_OUT; o++) acc[o] = 0.f;
    int g = -1;
    int cnt = 0;
    if (v < N_NODES) {
        g = gid[v];
        cnt = (quarter == 0) ? 1 : 0;
        const float4* h4 = (const float4*)h + v * 32 + quarter * 8;
        const float* wbase = Wmt + quarter * 36;
        #pragma unroll
        for (int kk = 0; kk < 8; kk++) {
            float4 hv = h4[kk];
            #pragma unroll
            for (int o = 0; o < D_OUT; o++) {
                float4 w = *(const float4*)(wbase + o * 144 + kk * 4);
                acc[o] += hv.x * w.x + hv.y * w.y + hv.z * w.z + hv.w * w.w;
            }
        }
    }

    #pragma unroll
    for (int d = 1; d < 64; d <<= 1) {
        int gp = __shfl_up(g, d, 64);
        int cp = __shfl_up(cnt, d, 64);
        bool take = (lane >= d) && (gp == g);
        #pragma unroll
        for (int o = 0; o < D_OUT; o++) {
            float ap = __shfl_up(acc[o], d, 64);
            if (take) acc[o] += ap;
        }
        if (take) cnt += cp;
    }
    int gn = __shfl_down(g, 1, 64);
    bool tail = (lane == 63) || (gn != g);
    if (tail && g >= 0) {
        #pragma unroll
        for (int o = 0; o < D_OUT; o++) atomicAdd(&hgp[g * D_OUT + o], acc[o]);
        if (cnt > 0) atomicAdd(&gcnt[g], cnt);
    }
}

// ---------------------------------------------------------------------------
// 9) Final: logits = hgp/cnt + bm ; log_softmax over axis 0 (graphs)
// ---------------------------------------------------------------------------
__global__ __launch_bounds__(512) void final_k(const float* __restrict__ hgp,
                                               const int* __restrict__ gcnt,
                                               const float* __restrict__ bm,
                                               float* __restrict__ out) {
    __shared__ float lg[N_GRAPHS * D_OUT];
    __shared__ float colm[D_OUT], colls[D_OUT];
    int tid = threadIdx.x;
    if (tid < N_GRAPHS * D_OUT) {
        int g = tid / D_OUT, o = tid % D_OUT;
        float c = (float)gcnt[g];
        lg[tid] = hgp[tid] / (c > 1.f ? c : 1.f) + bm[o];
    }
    __syncthreads();
    if (tid < D_OUT) {
        float m = -1e30f;
        for (int g = 0; g < N_GRAPHS; g++) m = fmaxf(m, lg[g * D_OUT + tid]);
        float s = 0.f;
        for (int g = 0; g < N_GRAPHS; g++) s += expf(lg[g * D_OUT + tid] - m);
        colm[tid] = m; colls[tid] = logf(s);
    }
    __syncthreads();
    if (tid < N_GRAPHS * D_OUT) {
        int o = tid % D_OUT;
        out[tid] = lg[tid] - colm[o] - colls[o];
    }
}

// ---------------------------------------------------------------------------
// Launch. packed[] aliases bufB head (dead before spmm#1 writes bufB).
// Total footprint 53,556,128 B.
// ---------------------------------------------------------------------------
extern "C" void kernel_launch(void* const* d_in, const int* in_sizes, int n_in,
                              void* d_out, int out_size, void* d_ws, size_t ws_size,
                              hipStream_t stream) {
    const float* h_in = (const float*)d_in[0];
    const int*   src  = (const int*)d_in[1];
    const int*   dst  = (const int*)d_in[2];
    const int*   gid  = (const int*)d_in[3];
    const float* W1 = (const float*)d_in[4];  const float* b1 = (const float*)d_in[5];
    const float* W2 = (const float*)d_in[6];  const float* b2 = (const float*)d_in[7];
    const float* W3 = (const float*)d_in[8];  const float* b3 = (const float*)d_in[9];
    const float* Wm = (const float*)d_in[10]; const float* bm = (const float*)d_in[11];

    char* ws = (char*)d_ws;
    int*            row_ptr = (int*)(ws + 0);                     // 50001 ints (pad 200,032)
    unsigned short* col16   = (unsigned short*)(ws + 200032);     // 1,600,000 B
    float*          nd      = (float*)(ws + 1800032);             // 200,000 B
    int*            out_deg = (int*)(ws + 2000032);               // 200,000 B  } zeroed
    int*            gcnt    = (int*)(ws + 2200032);               // 256 B      } together
    float*          hgp     = (float*)(ws + 2200288);             // 2,048 B    } 202,432 B
    int*            gh      = (int*)(ws + 2202464);               // 153,664 B
    float*          bufA    = (float*)(ws + 2356128);             // 25.6 MB
    float*          bufB    = (float*)(ws + 27956128);            // 25.6 MB -> 53,556,128
    unsigned int*   packed  = (unsigned int*)bufB;                // 3.2 MB alias

    hipMemsetAsync(out_deg, 0, 202432, stream);     // out_deg+gcnt+hgp

    part_hist<<<NBLK, 256, 0, stream>>>(dst, gh);
    part_scan<<<1, 1024, 0, stream>>>(gh);
    part_scatter<<<NBLK, 256, 0, stream>>>(src, dst, gh, packed, out_deg);
    bucket_csr<<<NB, 256, 0, stream>>>(packed, gh, col16, row_ptr, nd);
    prescale_k<<<6250, 256, 0, stream>>>(h_in, out_deg, bufA);

    spmm_k<<<6256, 256, 0, stream>>>(bufA, row_ptr, col16, nd, bufB);
    gemm_relu_k<0><<<196, 512, 0, stream>>>(bufB, W1, b1, out_deg, bufA);
    spmm_k<<<6256, 256, 0, stream>>>(bufA, row_ptr, col16, nd, bufB);
    gemm_relu_k<0><<<196, 512, 0, stream>>>(bufB, W2, b2, out_deg, bufA);
    spmm_k<<<6256, 256, 0, stream>>>(bufA, row_ptr, col16, nd, bufB);
    gemm_relu_k<1><<<196, 512, 0, stream>>>(bufB, W3, b3, out_deg, bufA);

    proj_readout_k<<<782, 256, 0, stream>>>(bufA, gid, Wm, hgp, gcnt);
    final_k<<<1, 512, 0, stream>>>(hgp, gcnt, bm, (float*)d_out);
}

// Round 9
// 458.049 us; speedup vs baseline: 1.4895x; 1.0195x over previous
//
#include <hip/hip_runtime.h>

#define N_NODES 50000
#define N_EDGES 800000
#define N_GRAPHS 50
#define D 128
#define D_OUT 10
#define PLANE_F4 200000   // per-slice plane: 50000 nodes * 4 float4 (16 floats)
#define NB 196            // coarse buckets: dst>>8 (49999>>8 == 195)
#define NBLK 196          // partition blocks (196*4096 >= 800000)
#define LCOL_CAP 3072     // staged cols per block (mean 1024, sigma ~32)

// ---------------------------------------------------------------------------
// 1) Coarse partition histogram for dst (LDS atomics only). The src
//    out-degree atomics live in part_scatter (overlap the vector pipes).
// ---------------------------------------------------------------------------
__global__ __launch_bounds__(256) void part_hist(const int* __restrict__ dst,
                                                 int* __restrict__ gh) {
    __shared__ int lh[NB];
    int tid = threadIdx.x, blk = blockIdx.x;
    if (tid < NB) lh[tid] = 0;
    __syncthreads();
    int base = blk * 4096;
    #pragma unroll
    for (int j = 0; j < 16; j++) {
        int i = base + j * 256 + tid;
        if (i < N_EDGES) atomicAdd(&lh[dst[i] >> 8], 1);     // LDS atomic
    }
    __syncthreads();
    if (tid < NB) gh[tid * NBLK + blk] = lh[tid];
}

// ---------------------------------------------------------------------------
// 2) Exclusive scan of gh[NB*NBLK = 38416]: round-3 chunked version
//    (coalesced: thread t loads base+t*4..+3). Round-6 lesson: the one-pass
//    contiguous-per-thread variant was uncoalesced on one CU -> 65us.
// ---------------------------------------------------------------------------
__global__ __launch_bounds__(1024) void part_scan(int* __restrict__ gh) {
    __shared__ int wsum[16];
    __shared__ int carry_s;
    const int N = NB * NBLK;            // 38416
    int tid = threadIdx.x;
    int lane = tid & 63, wid = tid >> 6;
    if (tid == 0) carry_s = 0;
    __syncthreads();
    for (int base = 0; base < N; base += 4096) {
        int i0 = base + tid * 4;
        int v0 = (i0 + 0 < N) ? gh[i0 + 0] : 0;
        int v1 = (i0 + 1 < N) ? gh[i0 + 1] : 0;
        int v2 = (i0 + 2 < N) ? gh[i0 + 2] : 0;
        int v3 = (i0 + 3 < N) ? gh[i0 + 3] : 0;
        int s = v0 + v1 + v2 + v3;
        int x = s;
        #pragma unroll
        for (int d = 1; d < 64; d <<= 1) {
            int y = __shfl_up(x, d, 64);
            if (lane >= d) x += y;
        }
        if (lane == 63) wsum[wid] = x;
        __syncthreads();
        if (wid == 0) {
            int t = (lane < 16) ? wsum[lane] : 0;
            #pragma unroll
            for (int d = 1; d < 16; d <<= 1) {
                int y = __shfl_up(t, d, 64);
                if (lane >= d) t += y;
            }
            if (lane < 16) wsum[lane] = t;
        }
        __syncthreads();
        int woff = (wid == 0) ? 0 : wsum[wid - 1];
        int run = carry_s + woff + (x - s);
        if (i0 + 0 < N) gh[i0 + 0] = run; run += v0;
        if (i0 + 1 < N) gh[i0 + 1] = run; run += v1;
        if (i0 + 2 < N) gh[i0 + 2] = run; run += v2;
        if (i0 + 3 < N) gh[i0 + 3] = run; run += v3;
        __syncthreads();
        if (tid == 0) carry_s += wsum[15];
        __syncthreads();
    }
}

// ---------------------------------------------------------------------------
// 3) Partition scatter (LDS cursors) + src out-degree histogram riding the
//    otherwise-idle device-atomic pipe.
// ---------------------------------------------------------------------------
__global__ __launch_bounds__(256) void part_scatter(const int* __restrict__ src,
                                                    const int* __restrict__ dst,
                                                    const int* __restrict__ gh,
                                                    unsigned int* __restrict__ packed,
                                                    int* __restrict__ out_deg) {
    __shared__ int lc[NB];
    int tid = threadIdx.x, blk = blockIdx.x;
    if (tid < NB) lc[tid] = gh[tid * NBLK + blk];
    __syncthreads();
    int base = blk * 4096;
    #pragma unroll
    for (int j = 0; j < 16; j++) {
        int i = base + j * 256 + tid;
        if (i < N_EDGES) {
            int d = dst[i];
            int s = src[i];
            atomicAdd(&out_deg[s], 1);               // device atomic (src stream)
            int p = atomicAdd(&lc[d >> 8], 1);       // LDS atomic
            packed[p] = ((unsigned int)(d & 255) << 16) | (unsigned int)s;
        }
    }
}

// ---------------------------------------------------------------------------
// 4) Per-bucket CSR build: one block per coarse bucket (~4096 edges, <=8192).
//    LDS-staged: 256-bin hist -> block scan -> row_ptr + nd + coalesced col16.
// ---------------------------------------------------------------------------
__global__ __launch_bounds__(256) void bucket_csr(const unsigned int* __restrict__ packed,
                                                  const int* __restrict__ gh,
                                                  unsigned short* __restrict__ col16,
                                                  int* __restrict__ row_ptr,
                                                  float* __restrict__ nd) {
    __shared__ unsigned int ep[8192];
    __shared__ unsigned short lcol[8192];
    __shared__ int hist[256], cur[256], wsum[4];
    int t = threadIdx.x, b = blockIdx.x;
    int nb = gh[b * NBLK];
    int ne = (b < NB - 1) ? gh[(b + 1) * NBLK] : N_EDGES;
    int cnt = ne - nb;
    if (cnt > 8192) cnt = 8192;         // statistically unreachable guard
    hist[t] = 0;
    __syncthreads();
    for (int i = t; i < cnt; i += 256) {
        unsigned int e = packed[nb + i];
        ep[i] = e;
        atomicAdd(&hist[e >> 16], 1);
    }
    __syncthreads();
    int v = hist[t];
    int lane = t & 63, w = t >> 6;
    int x = v;
    #pragma unroll
    for (int d = 1; d < 64; d <<= 1) {
        int y = __shfl_up(x, d, 64);
        if (lane >= d) x += y;
    }
    if (lane == 63) wsum[w] = x;
    __syncthreads();
    int add = 0;
    #pragma unroll
    for (int i = 0; i < 4; i++) if (i < w) add += wsum[i];
    int excl = add + x - v;
    cur[t] = excl;
    int node = b * 256 + t;
    if (node < N_NODES) {
        row_ptr[node] = nb + excl;
        int id = v > 1 ? v : 1;
        nd[node] = 1.0f / sqrtf((float)id);
    }
    if (b == NB - 1 && t == 0) row_ptr[N_NODES] = N_EDGES;
    __syncthreads();
    for (int i = t; i < cnt; i += 256) {
        unsigned int e = ep[i];
        int p = atomicAdd(&cur[e >> 16], 1);         // LDS atomic
        lcol[p] = (unsigned short)(e & 0xFFFF);
    }
    __syncthreads();
    for (int i = t; i < cnt; i += 256) col16[nb + i] = lcol[i];
}

// ---------------------------------------------------------------------------
// 5) Prescale + slice: xs[p][node][16] = out_deg[node]^-1/2 * h[node][p*16..].
// ---------------------------------------------------------------------------
__global__ __launch_bounds__(256) void prescale_k(const float* __restrict__ h,
                                                  const int* __restrict__ out_deg,
                                                  float* __restrict__ out) {
    int i = blockIdx.x * 256 + threadIdx.x;      // over 1,600,000 float4s
    if (i < N_NODES * 32) {
        int node = i >> 5;
        int kg = i & 31;
        float4 v = ((const float4*)h)[i];
        int od = out_deg[node];
        float s = 1.0f / sqrtf((float)(od > 1 ? od : 1));
        int p = kg >> 2, q = kg & 3;
        ((float4*)out)[p * PLANE_F4 + node * 4 + q] =
            make_float4(v.x * s, v.y * s, v.z * s, v.w * s);
    }
}

// ---------------------------------------------------------------------------
// 6) Feature-sliced SpMM. Shape LOCKED (grid 6256, 256 threads, slice=b&7,
//    64 nodes/blk, 4 lanes/node): FETCH 23.8MB measured 3x; r4/r5 shape
//    changes re-replicated to ~188MB. ROUND-9 single variable: the block's
//    contiguous col range (64 consecutive nodes -> one CSR span, mean 1024
//    edges) is cooperatively staged into LDS, coalesced, before the gather
//    loop. Rationale (r8 post-mortem): half the hot-loop vector-memory
//    instructions were scattered 2B col loads that the gathers chain-depend
//    on; staging removes ~45% of TA instruction pressure and breaks the
//    col->gather latency chain so the 8-deep gather pipeline fills.
//    Per-node global fallback covers the statistically-unreachable overflow.
// ---------------------------------------------------------------------------
__global__ __launch_bounds__(256) void spmm_k(const float* __restrict__ x,   // sliced
                                              const int* __restrict__ row_ptr,
                                              const unsigned short* __restrict__ col,
                                              const float* __restrict__ nd,
                                              float* __restrict__ out) {     // sliced
    __shared__ unsigned short lcol[LCOL_CAP];
    int b = blockIdx.x;
    int slice = b & 7;
    int n0b = (b >> 3) * 64;
    int nendb = n0b + 64; if (nendb > N_NODES) nendb = N_NODES;
    int e0 = row_ptr[n0b];
    int e1 = row_ptr[nendb];
    int cnt = e1 - e0;
    int staged = cnt < LCOL_CAP ? cnt : LCOL_CAP;
    for (int j = threadIdx.x; j < staged; j += 256) lcol[j] = col[e0 + j];
    __syncthreads();

    int node = n0b + (threadIdx.x >> 2);
    if (node >= N_NODES) return;
    int q = threadIdx.x & 3;
    int s = row_ptr[node];
    int e = row_ptr[node + 1];
    const float4* xp = (const float4*)x + slice * PLANE_F4;
    float4 a0 = make_float4(0.f, 0.f, 0.f, 0.f);
    float4 a1 = make_float4(0.f, 0.f, 0.f, 0.f);
    float4 a2 = make_float4(0.f, 0.f, 0.f, 0.f);
    float4 a3 = make_float4(0.f, 0.f, 0.f, 0.f);

    if (e - e0 <= staged) {
        // LDS col path (always taken in practice)
        const unsigned short* lc = lcol + (s - e0);
        int n = e - s;
        int i = 0;
        for (; i + 8 <= n; i += 8) {
            int c0 = lc[i],     c1 = lc[i + 1], c2 = lc[i + 2], c3 = lc[i + 3];
            int c4 = lc[i + 4], c5 = lc[i + 5], c6 = lc[i + 6], c7 = lc[i + 7];
            float4 h0 = xp[c0 * 4 + q];
            float4 h1 = xp[c1 * 4 + q];
            float4 h2 = xp[c2 * 4 + q];
            float4 h3 = xp[c3 * 4 + q];
            float4 h4 = xp[c4 * 4 + q];
            float4 h5 = xp[c5 * 4 + q];
            float4 h6 = xp[c6 * 4 + q];
            float4 h7 = xp[c7 * 4 + q];
            a0.x += h0.x; a0.y += h0.y; a0.z += h0.z; a0.w += h0.w;
            a1.x += h1.x; a1.y += h1.y; a1.z += h1.z; a1.w += h1.w;
            a2.x += h2.x; a2.y += h2.y; a2.z += h2.z; a2.w += h2.w;
            a3.x += h3.x; a3.y += h3.y; a3.z += h3.z; a3.w += h3.w;
            a0.x += h4.x; a0.y += h4.y; a0.z += h4.z; a0.w += h4.w;
            a1.x += h5.x; a1.y += h5.y; a1.z += h5.z; a1.w += h5.w;
            a2.x += h6.x; a2.y += h6.y; a2.z += h6.z; a2.w += h6.w;
            a3.x += h7.x; a3.y += h7.y; a3.z += h7.z; a3.w += h7.w;
        }
        for (; i + 4 <= n; i += 4) {
            int c0 = lc[i], c1 = lc[i + 1], c2 = lc[i + 2], c3 = lc[i + 3];
            float4 h0 = xp[c0 * 4 + q];
            float4 h1 = xp[c1 * 4 + q];
            float4 h2 = xp[c2 * 4 + q];
            float4 h3 = xp[c3 * 4 + q];
            a0.x += h0.x; a0.y += h0.y; a0.z += h0.z; a0.w += h0.w;
            a1.x += h1.x; a1.y += h1.y; a1.z += h1.z; a1.w += h1.w;
            a2.x += h2.x; a2.y += h2.y; a2.z += h2.z; a2.w += h2.w;
            a3.x += h3.x; a3.y += h3.y; a3.z += h3.z; a3.w += h3.w;
        }
        for (; i < n; i++) {
            float4 hv = xp[lc[i] * 4 + q];
            a0.x += hv.x; a0.y += hv.y; a0.z += hv.z; a0.w += hv.w;
        }
    } else {
        // global col fallback (statistically unreachable; correctness guard)
        int i = s;
        for (; i + 4 <= e; i += 4) {
            int c0 = col[i], c1 = col[i + 1], c2 = col[i + 2], c3 = col[i + 3];
            float4 h0 = xp[c0 * 4 + q];
            float4 h1 = xp[c1 * 4 + q];
            float4 h2 = xp[c2 * 4 + q];
            float4 h3 = xp[c3 * 4 + q];
            a0.x += h0.x; a0.y += h0.y; a0.z += h0.z; a0.w += h0.w;
            a1.x += h1.x; a1.y += h1.y; a1.z += h1.z; a1.w += h1.w;
            a2.x += h2.x; a2.y += h2.y; a2.z += h2.z; a2.w += h2.w;
            a3.x += h3.x; a3.y += h3.y; a3.z += h3.z; a3.w += h3.w;
        }
        for (; i < e; i++) {
            float4 hv = xp[col[i] * 4 + q];
            a0.x += hv.x; a0.y += hv.y; a0.z += hv.z; a0.w += hv.w;
        }
    }
    float ndv = nd[node];
    ((float4*)out)[slice * PLANE_F4 + node * 4 + q] =
        make_float4((a0.x + a1.x + a2.x + a3.x) * ndv,
                    (a0.y + a1.y + a2.y + a3.y) * ndv,
                    (a0.z + a1.z + a2.z + a3.z) * ndv,
                    (a0.w + a1.w + a2.w + a3.w) * ndv);
}

// ---------------------------------------------------------------------------
// 7) GEMM + bias + ReLU (known-good shape, unchanged).
//    MODE 0: out = odeg^-1/2 * relu(A@W+b), SLICED. MODE 1: normal layout.
// ---------------------------------------------------------------------------
template <int MODE>
__global__ __launch_bounds__(512) void gemm_relu_k(const float* __restrict__ A,  // sliced
                                                   const float* __restrict__ W,
                                                   const float* __restrict__ bias,
                                                   const int* __restrict__ odeg,
                                                   float* __restrict__ out) {
    __shared__ float As_t[128 * 256];   // 128 KB: [k][r]
    int tid = threadIdx.x;
    int row0 = blockIdx.x * 256;
    const float4* A4 = (const float4*)A;

    #pragma unroll
    for (int it = 0; it < 16; it++) {
        int linear = it * 512 + tid;       // 0..8191 float4s
        int p = linear >> 10;              // plane 0..7
        int rem = linear & 1023;
        int r = rem >> 2;                  // local row 0..255
        int q = rem & 3;                   // float4 within 16-float slice
        int row = row0 + r;
        float4 a = (row < N_NODES) ? A4[p * PLANE_F4 + row * 4 + q]
                                   : make_float4(0.f, 0.f, 0.f, 0.f);
        int kb = p * 16 + q * 4;
        As_t[(kb + 0) * 256 + r] = a.x;
        As_t[(kb + 1) * 256 + r] = a.y;
        As_t[(kb + 2) * 256 + r] = a.z;
        As_t[(kb + 3) * 256 + r] = a.w;
    }
    __syncthreads();

    int tc = tid & 15;    // col group: cols tc*8 .. +8
    int tr = tid >> 4;    // 0..31 : rows tr*8 .. +8
    float acc[8][8];
    #pragma unroll
    for (int r = 0; r < 8; r++)
        #pragma unroll
        for (int c = 0; c < 8; c++) acc[r][c] = 0.f;

    const float4* W4 = (const float4*)W;
    #pragma unroll 2
    for (int k = 0; k < 128; k++) {
        float4 w0 = W4[k * 32 + tc * 2];
        float4 w1 = W4[k * 32 + tc * 2 + 1];
        float4 a0 = *(const float4*)(As_t + k * 256 + tr * 8);
        float4 a1 = *(const float4*)(As_t + k * 256 + tr * 8 + 4);
        float av[8] = {a0.x, a0.y, a0.z, a0.w, a1.x, a1.y, a1.z, a1.w};
        float wv[8] = {w0.x, w0.y, w0.z, w0.w, w1.x, w1.y, w1.z, w1.w};
        #pragma unroll
        for (int rr = 0; rr < 8; rr++)
            #pragma unroll
            for (int cc = 0; cc < 8; cc++)
                acc[rr][cc] = fmaf(av[rr], wv[cc], acc[rr][cc]);
    }

    float4 bv0 = ((const float4*)bias)[tc * 2];
    float4 bv1 = ((const float4*)bias)[tc * 2 + 1];
    #pragma unroll
    for (int rr = 0; rr < 8; rr++) {
        int row = row0 + tr * 8 + rr;
        if (row < N_NODES) {
            float4 o0, o1;
            o0.x = fmaxf(acc[rr][0] + bv0.x, 0.f);
            o0.y = fmaxf(acc[rr][1] + bv0.y, 0.f);
            o0.z = fmaxf(acc[rr][2] + bv0.z, 0.f);
            o0.w = fmaxf(acc[rr][3] + bv0.w, 0.f);
            o1.x = fmaxf(acc[rr][4] + bv1.x, 0.f);
            o1.y = fmaxf(acc[rr][5] + bv1.y, 0.f);
            o1.z = fmaxf(acc[rr][6] + bv1.z, 0.f);
            o1.w = fmaxf(acc[rr][7] + bv1.w, 0.f);
            if (MODE == 0) {
                int od = odeg[row];
                float s = 1.0f / sqrtf((float)(od > 1 ? od : 1));
                o0.x *= s; o0.y *= s; o0.z *= s; o0.w *= s;
                o1.x *= s; o1.y *= s; o1.z *= s; o1.w *= s;
                int p = tc >> 1;
                int q0 = (tc & 1) * 2;
                ((float4*)out)[p * PLANE_F4 + row * 4 + q0] = o0;
                ((float4*)out)[p * PLANE_F4 + row * 4 + q0 + 1] = o1;
            } else {
                ((float4*)out)[row * 32 + tc * 2] = o0;
                ((float4*)out)[row * 32 + tc * 2 + 1] = o1;
            }
        }
    }
}

// ---------------------------------------------------------------------------
// 8) Fused projection + readout (unchanged).
// ---------------------------------------------------------------------------
__global__ __launch_bounds__(256) void proj_readout_k(const float* __restrict__ h,
                                                      const int* __restrict__ gid,
                                                      const float* __restrict__ Wm,
                                                      float* __restrict__ hgp,
                                                      int* __restrict__ gcnt) {
    __shared__ float Wmt[10 * 144];
    int tid = threadIdx.x;
    for (int i = tid; i < 1280; i += 256) {
        int k = i / 10, o = i % 10;
        Wmt[o * 144 + k + 4 * (k >> 5)] = Wm[i];
    }
    __syncthreads();

    int v = blockIdx.x * 64 + (tid >> 2);
    int quarter = tid & 3;
    int lane = tid & 63;

    float acc[D_OUT];
    #pragma unroll
    for (int o = 0; o < D_OUT; o++) acc[o] = 0.f;
    int g = -1;
    int cnt = 0;
    if (v < N_NODES) {
        g = gid[v];
        cnt = (quarter == 0) ? 1 : 0;
        const float4* h4 = (const float4*)h + v * 32 + quarter * 8;
        const float* wbase = Wmt + quarter * 36;
        #pragma unroll
        for (int kk = 0; kk < 8; kk++) {
            float4 hv = h4[kk];
            #pragma unroll
            for (int o = 0; o < D_OUT; o++) {
                float4 w = *(const float4*)(wbase + o * 144 + kk * 4);
                acc[o] += hv.x * w.x + hv.y * w.y + hv.z * w.z + hv.w * w.w;
            }
        }
    }

    #pragma unroll
    for (int d = 1; d < 64; d <<= 1) {
        int gp = __shfl_up(g, d, 64);
        int cp = __shfl_up(cnt, d, 64);
        bool take = (lane >= d) && (gp == g);
        #pragma unroll
        for (int o = 0; o < D_OUT; o++) {
            float ap = __shfl_up(acc[o], d, 64);
            if (take) acc[o] += ap;
        }
        if (take) cnt += cp;
    }
    int gn = __shfl_down(g, 1, 64);
    bool tail = (lane == 63) || (gn != g);
    if (tail && g >= 0) {
        #pragma unroll
        for (int o = 0; o < D_OUT; o++) atomicAdd(&hgp[g * D_OUT + o], acc[o]);
        if (cnt > 0) atomicAdd(&gcnt[g], cnt);
    }
}

// ---------------------------------------------------------------------------
// 9) Final: logits = hgp/cnt + bm ; log_softmax over axis 0 (graphs)
// ---------------------------------------------------------------------------
__global__ __launch_bounds__(512) void final_k(const float* __restrict__ hgp,
                                               const int* __restrict__ gcnt,
                                               const float* __restrict__ bm,
                                               float* __restrict__ out) {
    __shared__ float lg[N_GRAPHS * D_OUT];
    __shared__ float colm[D_OUT], colls[D_OUT];
    int tid = threadIdx.x;
    if (tid < N_GRAPHS * D_OUT) {
        int g = tid / D_OUT, o = tid % D_OUT;
        float c = (float)gcnt[g];
        lg[tid] = hgp[tid] / (c > 1.f ? c : 1.f) + bm[o];
    }
    __syncthreads();
    if (tid < D_OUT) {
        float m = -1e30f;
        for (int g = 0; g < N_GRAPHS; g++) m = fmaxf(m, lg[g * D_OUT + tid]);
        float s = 0.f;
        for (int g = 0; g < N_GRAPHS; g++) s += expf(lg[g * D_OUT + tid] - m);
        colm[tid] = m; colls[tid] = logf(s);
    }
    __syncthreads();
    if (tid < N_GRAPHS * D_OUT) {
        int o = tid % D_OUT;
        out[tid] = lg[tid] - colm[o] - colls[o];
    }
}

// ---------------------------------------------------------------------------
// Launch. packed[] aliases bufB head (dead before spmm#1 writes bufB).
// Total footprint 53,556,128 B.
// ---------------------------------------------------------------------------
extern "C" void kernel_launch(void* const* d_in, const int* in_sizes, int n_in,
                              void* d_out, int out_size, void* d_ws, size_t ws_size,
                              hipStream_t stream) {
    const float* h_in = (const float*)d_in[0];
    const int*   src  = (const int*)d_in[1];
    const int*   dst  = (const int*)d_in[2];
    const int*   gid  = (const int*)d_in[3];
    const float* W1 = (const float*)d_in[4];  const float* b1 = (const float*)d_in[5];
    const float* W2 = (const float*)d_in[6];  const float* b2 = (const float*)d_in[7];
    const float* W3 = (const float*)d_in[8];  const float* b3 = (const float*)d_in[9];
    const float* Wm = (const float*)d_in[10]; const float* bm = (const float*)d_in[11];

    char* ws = (char*)d_ws;
    int*            row_ptr = (int*)(ws + 0);                     // 50001 ints (pad 200,032)
    unsigned short* col16   = (unsigned short*)(ws + 200032);     // 1,600,000 B
    float*          nd      = (float*)(ws + 1800032);             // 200,000 B
    int*            out_deg = (int*)(ws + 2000032);               // 200,000 B  } zeroed
    int*            gcnt    = (int*)(ws + 2200032);               // 256 B      } together
    float*          hgp     = (float*)(ws + 2200288);             // 2,048 B    } 202,432 B
    int*            gh      = (int*)(ws + 2202464);               // 153,664 B
    float*          bufA    = (float*)(ws + 2356128);             // 25.6 MB
    float*          bufB    = (float*)(ws + 27956128);            // 25.6 MB -> 53,556,128
    unsigned int*   packed  = (unsigned int*)bufB;                // 3.2 MB alias

    hipMemsetAsync(out_deg, 0, 202432, stream);     // out_deg+gcnt+hgp

    part_hist<<<NBLK, 256, 0, stream>>>(dst, gh);
    part_scan<<<1, 1024, 0, stream>>>(gh);
    part_scatter<<<NBLK, 256, 0, stream>>>(src, dst, gh, packed, out_deg);
    bucket_csr<<<NB, 256, 0, stream>>>(packed, gh, col16, row_ptr, nd);
    prescale_k<<<6250, 256, 0, stream>>>(h_in, out_deg, bufA);

    spmm_k<<<6256, 256, 0, stream>>>(bufA, row_ptr, col16, nd, bufB);
    gemm_relu_k<0><<<196, 512, 0, stream>>>(bufB, W1, b1, out_deg, bufA);
    spmm_k<<<6256, 256, 0, stream>>>(bufA, row_ptr, col16, nd, bufB);
    gemm_relu_k<0><<<196, 512, 0, stream>>>(bufB, W2, b2, out_deg, bufA);
    spmm_k<<<6256, 256, 0, stream>>>(bufA, row_ptr, col16, nd, bufB);
    gemm_relu_k<1><<<196, 512, 0, stream>>>(bufB, W3, b3, out_deg, bufA);

    proj_readout_k<<<782, 256, 0, stream>>>(bufA, gid, Wm, hgp, gcnt);
    final_k<<<1, 512, 0, stream>>>(hgp, gcnt, bm, (float*)d_out);
}